// Round 6
// baseline (315.617 us; speedup 1.0000x reference)
//
#include <hip/hip_runtime.h>
#include <hip/hip_bf16.h>

#define PARTS 16
#define NB 128
#define CH 256
#define SL 64
#define HIDN 64

typedef unsigned short u16;
typedef unsigned int u32;
typedef unsigned short ushort8 __attribute__((ext_vector_type(8)));
typedef unsigned short ushort4v __attribute__((ext_vector_type(4)));
typedef __attribute__((ext_vector_type(8))) short short8v;
typedef __attribute__((ext_vector_type(4))) float f32x4;

__device__ __forceinline__ float bf2f(u16 u) {
  union { unsigned u; float f; } t; t.u = ((unsigned)u) << 16; return t.f;
}
__device__ __forceinline__ u16 f2bf(float f) {
  union { float f; unsigned u; } t; t.f = f;
  unsigned u = t.u;
  u += 0x7FFFu + ((u >> 16) & 1u);
  return (u16)(u >> 16);
}
// packed pair convert: low16 = bf16(a), high16 = bf16(b) -> v_cvt_pk_bf16_f32
__device__ __forceinline__ unsigned pk2bf(float a, float b) {
  float2 f; f.x = a; f.y = b;
  union { __hip_bfloat162 h; unsigned u; } cv;
  cv.h = __float22bfloat162_rn(f);
  return cv.u;
}

// ===================== weight conversion prepass =====================
// out[p][t][x] = bf16(in[p][x][t]);  NX = 16384 fixed, NT = 3 or 1.
__global__ void cvt_tap(const float* __restrict__ in, u16* __restrict__ out, int NT) {
  const int i = blockIdx.x * 256 + threadIdx.x;   // p*16384 + x, exact grid
  const int p = i >> 14, xid = i & 16383;
  const float* src = in + (size_t)i * NT;
  for (int t = 0; t < NT; ++t)
    out[(size_t)(p * NT + t) * 16384 + xid] = f2bf(src[t]);
}

// ===================== MFMA main kernel: wave-private H =====================
// 256 threads / 4 waves. Wave w owns s-tile [w*16, w*16+16) for BOTH phases.
// Phase A computes all 64 h for the wave's 16 s -> H stays in registers
// (packed bf16). Phase B B-frags (k=h) assembled in-register via __shfl;
// tap-shift halo columns (s-tile edges) via a 1.5 KB LDS buffer. No ht LDS:
// total LDS 40448 B -> 4 blocks/CU -> 16 waves/CU (vs round-3's 12).
//
// XT[r][c]: r = s+2, rows 0..67 (s=-2..65), 256 cols, XOR-swizzled, pad rows
// 0,1,66,67 = 0.
#define XROWS 68

__device__ __forceinline__ int xsw(int r, int c) { return (r * 256 + c) ^ ((r & 7) << 3); }

// Assemble a phase-B B-frag for k-step `ks` (h in [ks*32, ks*32+32)), tap
// shift `dlt` in {-1,0,+1}, from this wave's packed H (Hpk[mt][0..1], mt =
// h>>4). Target lane (col,kg) needs h = ks*32 + kg*8 + j, j=0..7 at column
// col+dlt. Holder lane = (2*(kg&1) + (j>>2))*16 + (col+dlt), pk-reg = (j&3)>>1,
// mt = 2ks + (kg>>1) -> shuffle both mt candidates, select (runtime reg-index
// would spill to scratch, rule #20). Edge lanes (col+dlt outside [0,16))
// override from the halo LDS (zeros at global s=-1 / s=64: conv pad).
#define ASM_FRAG(dst, Hpk, ks, dlt, br) do {                                   \
  const int colD_ = col + (dlt);                                               \
  const int laneA_ = (2 * (kg & 1)) * 16 + (colD_ & 15);                       \
  const int laneB_ = laneA_ + 16;                                              \
  const u32 lo0_ = __shfl(Hpk[2*(ks)][0], laneA_);                             \
  const u32 hi0_ = __shfl(Hpk[2*(ks)+1][0], laneA_);                           \
  const u32 lo1_ = __shfl(Hpk[2*(ks)][1], laneA_);                             \
  const u32 hi1_ = __shfl(Hpk[2*(ks)+1][1], laneA_);                           \
  const u32 lo2_ = __shfl(Hpk[2*(ks)][0], laneB_);                             \
  const u32 hi2_ = __shfl(Hpk[2*(ks)+1][0], laneB_);                           \
  const u32 lo3_ = __shfl(Hpk[2*(ks)][1], laneB_);                             \
  const u32 hi3_ = __shfl(Hpk[2*(ks)+1][1], laneB_);                           \
  const bool hiMt_ = (kg >> 1) != 0;                                           \
  union { short8v v; u32 u[4]; } fu_;                                          \
  fu_.u[0] = hiMt_ ? hi0_ : lo0_;  fu_.u[1] = hiMt_ ? hi1_ : lo1_;             \
  fu_.u[2] = hiMt_ ? hi2_ : lo2_;  fu_.u[3] = hiMt_ ? hi3_ : lo3_;             \
  if (colD_ < 0 || colD_ > 15) {                                               \
    const int sg_ = sb + colD_;                                                \
    if (sg_ < 0 || sg_ > 63) {                                                 \
      fu_.u[0] = 0; fu_.u[1] = 0; fu_.u[2] = 0; fu_.u[3] = 0;                  \
    } else {                                                                   \
      const int idx_ = (colD_ < 0) ? 2 * (w - 1) : 2 * w + 1;                  \
      fu_.v = *(const short8v*)&edge[br][idx_][(ks) * 32 + kg * 8];            \
    }                                                                          \
  }                                                                            \
  dst = fu_.v;                                                                 \
} while (0)

// __launch_bounds__(256, 4): blocks-reading -> 4 blk x 4 waves / 4 SIMD = 4
// waves/EU -> VGPR cap 128; waves-reading -> 4 -> cap 128. Same either way
// (the r4/r5 semantics ambiguity is neutralized). LDS 40448 -> 4 blocks/CU.
__global__ __launch_bounds__(256, 4) void tfa_mfma(
    const float* __restrict__ x,
    const u16* __restrict__ wsb,
    float* __restrict__ out)
{
  const u16* W1A = wsb;                 // [p][t][h][c]  786432
  const u16* W3A = wsb + 786432;        // [p][t][h][c]  786432
  const u16* W1B = wsb + 1572864;       // [p][c][h]     262144
  const u16* W3B = wsb + 1835008;       // [p][t][c][h]  786432

  __shared__ __attribute__((aligned(16))) u16 xt[XROWS * 256];   // 34816 B
  __shared__ __attribute__((aligned(16))) u16 edge[2][6][64];    //  1536 B halo
  __shared__ __attribute__((aligned(16))) float pmax[4][256];    //  4096 B

  const int tid = threadIdx.x;
  const int bid = blockIdx.x;          // p*NB + n
  const int p = bid >> 7;
  const int lane = tid & 63;
  const int w = tid >> 6;              // wave id 0..3
  const int col = lane & 15;
  const int kg = lane >> 4;
  const int sb = w * 16;               // wave's s-tile base

  // ---- zero xt pad rows ----
  if (tid < 128) {
    const int rr4 = (tid >> 5);
    const int r = (rr4 == 0) ? 0 : (rr4 == 1) ? 1 : (rr4 == 2) ? 66 : 67;
    const int c = (tid & 31) * 8;
    *(ushort8*)&xt[xsw(r, c)] = (ushort8)0;
  }

  // ---- stage x -> XT (transposed, bf16, swizzled); lane = s, wave covers 64 c ----
  {
    const float* xb = x + (size_t)bid * (CH * SL);
    const int s = lane;
    const int r = s + 2;
    #pragma unroll
    for (int j = 0; j < 8; ++j) {
      const int c0 = w * 64 + j * 8;
      union { ushort8 v; unsigned u[4]; } ov;
      #pragma unroll
      for (int k = 0; k < 4; ++k) {
        const float fa = xb[(c0 + 2 * k) * 64 + s];
        const float fb = xb[(c0 + 2 * k + 1) * 64 + s];
        ov.u[k] = pk2bf(fa, fb);
      }
      *(ushort8*)&xt[xsw(r, c0)] = ov.v;
    }
  }
  __syncthreads();

  // ---- phase A: all 64 h x this wave's 16 s, both branches ----
  // D[mt]: lane holds h = mt*16 + kg*4 + q, s = sb + col.
  u32 H1pk[4][2], H3pk[4][2];
  {
    f32x4 acc1[4], acc3[4];
    #pragma unroll
    for (int mt = 0; mt < 4; ++mt) { acc1[mt] = (f32x4)0.f; acc3[mt] = (f32x4)0.f; }

    #pragma unroll 1
    for (int ks = 0; ks < 8; ++ks) {
      const int kc = ks * 32 + kg * 8;
      short8v b[3];
      #pragma unroll
      for (int t = 0; t < 3; ++t)
        b[t] = *(const short8v*)&xt[xsw(sb + col + t + 1, kc)];  // s + (t-1) + 2
      #pragma unroll
      for (int mt = 0; mt < 4; ++mt) {
        const size_t ha = (size_t)(mt * 16 + col) * 256 + kc;
        #pragma unroll
        for (int t = 0; t < 3; ++t) {
          const size_t tb = (size_t)((p * 3 + t) * 64) * 256;
          const short8v a1 = *(const short8v*)&W1A[tb + ha];
          acc1[mt] = __builtin_amdgcn_mfma_f32_16x16x32_bf16(a1, b[t], acc1[mt], 0, 0, 0);
          const short8v a3 = *(const short8v*)&W3A[tb + ha];
          acc3[mt] = __builtin_amdgcn_mfma_f32_16x16x32_bf16(a3, b[t], acc3[mt], 0, 0, 0);
        }
      }
    }

    // LeakyReLU + pack to bf16 pairs (h ascending within each u32 pair)
    #pragma unroll
    for (int mt = 0; mt < 4; ++mt) {
      float v1[4], v3[4];
      #pragma unroll
      for (int q = 0; q < 4; ++q) {
        const float a = acc1[mt][q]; v1[q] = a >= 0.f ? a : 0.01f * a;
        const float bq = acc3[mt][q]; v3[q] = bq >= 0.f ? bq : 0.01f * bq;
      }
      H1pk[mt][0] = pk2bf(v1[0], v1[1]); H1pk[mt][1] = pk2bf(v1[2], v1[3]);
      H3pk[mt][0] = pk2bf(v3[0], v3[1]); H3pk[mt][1] = pk2bf(v3[2], v3[3]);
    }

    // halo: publish edge columns. col 15 of wave w -> left-halo of wave w+1
    // (idx 2w); col 0 of wave w -> right-halo of wave w-1 (idx 2(w-1)+1).
    if (col == 15 && w < 3) {
      #pragma unroll
      for (int mt = 0; mt < 4; ++mt) {
        *(uint2*)&edge[0][2 * w][mt * 16 + kg * 4] = make_uint2(H1pk[mt][0], H1pk[mt][1]);
        *(uint2*)&edge[1][2 * w][mt * 16 + kg * 4] = make_uint2(H3pk[mt][0], H3pk[mt][1]);
      }
    }
    if (col == 0 && w > 0) {
      const int idx = 2 * (w - 1) + 1;
      #pragma unroll
      for (int mt = 0; mt < 4; ++mt) {
        *(uint2*)&edge[0][idx][mt * 16 + kg * 4] = make_uint2(H1pk[mt][0], H1pk[mt][1]);
        *(uint2*)&edge[1][idx][mt * 16 + kg * 4] = make_uint2(H3pk[mt][0], H3pk[mt][1]);
      }
    }
  }
  __syncthreads();

  // ---- assemble all phase-B B-frags once (c-independent) ----
  short8v f1[2], f3[2][3];
  ASM_FRAG(f1[0],    H1pk, 0,  0, 0);
  ASM_FRAG(f1[1],    H1pk, 1,  0, 0);
  ASM_FRAG(f3[0][0], H3pk, 0, -1, 1);
  ASM_FRAG(f3[0][1], H3pk, 0,  0, 1);
  ASM_FRAG(f3[0][2], H3pk, 0, +1, 1);
  ASM_FRAG(f3[1][0], H3pk, 1, -1, 1);
  ASM_FRAG(f3[1][1], H3pk, 1,  0, 1);
  ASM_FRAG(f3[1][2], H3pk, 1, +1, 1);

  // ---- phase B: conv2 both branches + gates + pools, c in quarters ----
  #pragma unroll 1
  for (int cq = 0; cq < 4; ++cq) {
    f32x4 acc[4];
    #pragma unroll
    for (int mtc = 0; mtc < 4; ++mtc) acc[mtc] = (f32x4)0.f;

    // branch 1 (k1)
    #pragma unroll
    for (int ks = 0; ks < 2; ++ks) {
      #pragma unroll
      for (int mtc = 0; mtc < 4; ++mtc) {
        const int c = cq * 64 + mtc * 16 + col;
        const short8v a = *(const short8v*)&W1B[((size_t)p * 256 + c) * 64 + ks * 32 + kg * 8];
        acc[mtc] = __builtin_amdgcn_mfma_f32_16x16x32_bf16(a, f1[ks], acc[mtc], 0, 0, 0);
      }
    }

    // gates g1 = sigmoid(L1), packed bf16 pairs
    u32 g1p[4][2];
    #pragma unroll
    for (int mtc = 0; mtc < 4; ++mtc) {
      #pragma unroll
      for (int j = 0; j < 2; ++j) {
        const float ga = 1.f / (1.f + __expf(-acc[mtc][2 * j]));
        const float gb = 1.f / (1.f + __expf(-acc[mtc][2 * j + 1]));
        g1p[mtc][j] = pk2bf(ga, gb);
      }
      acc[mtc] = (f32x4)0.f;       // reuse for branch 3
    }

    // branch 3 (k3)
    #pragma unroll
    for (int ks = 0; ks < 2; ++ks) {
      #pragma unroll
      for (int t = 0; t < 3; ++t) {
        #pragma unroll
        for (int mtc = 0; mtc < 4; ++mtc) {
          const int c = cq * 64 + mtc * 16 + col;
          const short8v a = *(const short8v*)&W3B[(size_t)((p * 3 + t) * 256 + c) * 64 + ks * 32 + kg * 8];
          acc[mtc] = __builtin_amdgcn_mfma_f32_16x16x32_bf16(a, f3[ks][t], acc[mtc], 0, 0, 0);
        }
      }
    }

    // epilogue: pools from XT + gates + partial max over this wave's 16 s
    #pragma unroll
    for (int mtc = 0; mtc < 4; ++mtc) {
      const int c4 = cq * 64 + mtc * 16 + kg * 4;   // D rows: 4 consecutive c
      const int sg = sb + col;                       // D col: global s
      const ushort4v vm2 = *(const ushort4v*)&xt[xsw(sg,     c4)];
      const ushort4v vm1 = *(const ushort4v*)&xt[xsw(sg + 1, c4)];
      const ushort4v v0  = *(const ushort4v*)&xt[xsw(sg + 2, c4)];
      const ushort4v vp1 = *(const ushort4v*)&xt[xsw(sg + 3, c4)];
      const ushort4v vp2 = *(const ushort4v*)&xt[xsw(sg + 4, c4)];
      const float NI = -INFINITY;
      float ft[4];
      #pragma unroll
      for (int q = 0; q < 4; ++q) {
        const float xm2 = bf2f(vm2[q]), xm1 = bf2f(vm1[q]), x0 = bf2f(v0[q]);
        const float xp1 = bf2f(vp1[q]), xp2 = bf2f(vp2[q]);
        const float mx3 = fmaxf(x0, fmaxf(sg >= 1 ? xm1 : NI, sg <= 62 ? xp1 : NI));
        const float mx5 = fmaxf(mx3, fmaxf(sg >= 2 ? xm2 : NI, sg <= 61 ? xp2 : NI));
        const float av3 = (xm1 + x0 + xp1) * (1.f / 3.f);
        const float av5 = (xm2 + xm1 + x0 + xp1 + xp2) * 0.2f;
        const float g1 = bf2f((u16)(g1p[mtc][q >> 1] >> ((q & 1) * 16)));
        const float g3 = 1.f / (1.f + __expf(-acc[mtc][q]));
        ft[q] = (av3 + mx3) * g1 + (av5 + mx5) * g3;
      }
      float fmx0 = ft[0], fmx1 = ft[1], fmx2 = ft[2], fmx3 = ft[3];
      #pragma unroll
      for (int off = 1; off < 16; off <<= 1) {      // max over the 16-s tile
        fmx0 = fmaxf(fmx0, __shfl_xor(fmx0, off));
        fmx1 = fmaxf(fmx1, __shfl_xor(fmx1, off));
        fmx2 = fmaxf(fmx2, __shfl_xor(fmx2, off));
        fmx3 = fmaxf(fmx3, __shfl_xor(fmx3, off));
      }
      if (col == 0) {
        float4 o; o.x = fmx0; o.y = fmx1; o.z = fmx2; o.w = fmx3;
        *(float4*)&pmax[w][c4] = o;
      }
    }
  }
  __syncthreads();

  // ---- final: combine the 4 wave-partial maxes, write out ----
  {
    const int c = tid;
    const float m = fmaxf(fmaxf(pmax[0][c], pmax[1][c]),
                          fmaxf(pmax[2][c], pmax[3][c]));
    out[(size_t)bid * 256 + c] = m;
  }
}

// ===================== fallback vector kernel (round-1, correct) =====================
#define XROW 72
#define HROW 72

__global__ __launch_bounds__(256, 2) void tfa_kernel(
    const float* __restrict__ x,
    const float* __restrict__ w1a,
    const float* __restrict__ w1b,
    const float* __restrict__ w3a,
    const float* __restrict__ w3b,
    float* __restrict__ out)
{
  __shared__ __attribute__((aligned(16))) u16 x_s[8 + CH * XROW];
  __shared__ __attribute__((aligned(16))) u16 h1_s[8 + HIDN * HROW];
  __shared__ __attribute__((aligned(16))) u16 h3_s[8 + HIDN * HROW];

  const int tid = threadIdx.x;
  const int bid = blockIdx.x;
  const int p = bid >> 7;

  {
    const ushort8 z = {0, 0, 0, 0, 0, 0, 0, 0};
    for (int i = tid; i < 257; i += 256) {
      u16* dst = (i == 0) ? &x_s[0] : &x_s[8 + (i - 1) * XROW + 64];
      *(ushort8*)dst = z;
    }
    if (tid < 65) {
      u16* d1 = (tid == 0) ? &h1_s[0] : &h1_s[8 + (tid - 1) * HROW + 64];
      *(ushort8*)d1 = z;
      u16* d3 = (tid == 0) ? &h3_s[0] : &h3_s[8 + (tid - 1) * HROW + 64];
      *(ushort8*)d3 = z;
    }
  }

  const float* xblk = x + (size_t)bid * (CH * SL);
  #pragma unroll
  for (int j = 0; j < 16; ++j) {
    const int g = tid + 256 * j;
    const float4 v = ((const float4*)xblk)[g];
    const int c = g >> 4, s4 = g & 15;
    ushort4v o;
    o[0] = f2bf(v.x); o[1] = f2bf(v.y); o[2] = f2bf(v.z); o[3] = f2bf(v.w);
    *(ushort4v*)&x_s[8 + c * XROW + s4 * 4] = o;
  }
  __syncthreads();

  {
    const int h = tid >> 2;
    const int sg = tid & 3;
    const int sb = sg << 4;
    float acc1[16], acc3[16];
    #pragma unroll
    for (int i = 0; i < 16; ++i) { acc1[i] = 0.f; acc3[i] = 0.f; }

    const float* w1a_p = w1a + ((size_t)p * HIDN + h) * (CH * 3);
    const float* w3a_p = w3a + ((size_t)p * HIDN + h) * (CH * 3);

    for (int c4 = 0; c4 < CH; c4 += 4) {
      const float4 a0v = *(const float4*)&w1a_p[c4 * 3];
      const float4 a1v = *(const float4*)&w1a_p[c4 * 3 + 4];
      const float4 a2v = *(const float4*)&w1a_p[c4 * 3 + 8];
      const float4 b0v = *(const float4*)&w3a_p[c4 * 3];
      const float4 b1v = *(const float4*)&w3a_p[c4 * 3 + 4];
      const float4 b2v = *(const float4*)&w3a_p[c4 * 3 + 8];
      float wa[12], wb[12];
      wa[0]=a0v.x; wa[1]=a0v.y; wa[2]=a0v.z; wa[3]=a0v.w;
      wa[4]=a1v.x; wa[5]=a1v.y; wa[6]=a1v.z; wa[7]=a1v.w;
      wa[8]=a2v.x; wa[9]=a2v.y; wa[10]=a2v.z; wa[11]=a2v.w;
      wb[0]=b0v.x; wb[1]=b0v.y; wb[2]=b0v.z; wb[3]=b0v.w;
      wb[4]=b1v.x; wb[5]=b1v.y; wb[6]=b1v.z; wb[7]=b1v.w;
      wb[8]=b2v.x; wb[9]=b2v.y; wb[10]=b2v.z; wb[11]=b2v.w;

      #pragma unroll
      for (int cc = 0; cc < 4; ++cc) {
        const int c = c4 + cc;
        const ushort8 w0v = *(const ushort8*)&x_s[c * XROW + sb];
        const ushort8 w1v = *(const ushort8*)&x_s[c * XROW + sb + 8];
        const ushort8 w2v = *(const ushort8*)&x_s[c * XROW + sb + 16];
        const ushort8 w3v = *(const ushort8*)&x_s[c * XROW + sb + 24];
        float xf[19];
        xf[0] = bf2f(w0v[7]);
        #pragma unroll
        for (int d = 0; d < 8; ++d) xf[1 + d] = bf2f(w1v[d]);
        #pragma unroll
        for (int d = 0; d < 8; ++d) xf[9 + d] = bf2f(w2v[d]);
        xf[17] = bf2f(w3v[0]);
        xf[18] = bf2f(w3v[1]);

        const float a0 = wa[cc * 3], a1 = wa[cc * 3 + 1], a2 = wa[cc * 3 + 2];
        const float b0 = wb[cc * 3], b1 = wb[cc * 3 + 1], b2 = wb[cc * 3 + 2];
        #pragma unroll
        for (int i = 0; i < 16; ++i) {
          const float xm = xf[i], x0 = xf[i + 1], xp = xf[i + 2];
          acc1[i] = fmaf(a0, xm, fmaf(a1, x0, fmaf(a2, xp, acc1[i])));
          acc3[i] = fmaf(b0, xm, fmaf(b1, x0, fmaf(b2, xp, acc3[i])));
        }
      }
    }

    ushort8 o1a, o1b, o3a, o3b;
    #pragma unroll
    for (int i = 0; i < 8; ++i) {
      float v1 = acc1[i];     v1 = v1 >= 0.f ? v1 : 0.01f * v1;
      float v3 = acc3[i];     v3 = v3 >= 0.f ? v3 : 0.01f * v3;
      o1a[i] = f2bf(v1); o3a[i] = f2bf(v3);
      float u1 = acc1[i + 8]; u1 = u1 >= 0.f ? u1 : 0.01f * u1;
      float u3 = acc3[i + 8]; u3 = u3 >= 0.f ? u3 : 0.01f * u3;
      o1b[i] = f2bf(u1); o3b[i] = f2bf(u3);
    }
    *(ushort8*)&h1_s[8 + h * HROW + sb]     = o1a;
    *(ushort8*)&h1_s[8 + h * HROW + sb + 8] = o1b;
    *(ushort8*)&h3_s[8 + h * HROW + sb]     = o3a;
    *(ushort8*)&h3_s[8 + h * HROW + sb + 8] = o3b;
  }
  __syncthreads();

  {
    const int lane = tid & 63;
    const int wid = __builtin_amdgcn_readfirstlane(tid >> 6);
    const int s = lane;
    const float* w1b_p = w1b + (size_t)p * (CH * HIDN);
    const float* w3b_p = w3b + (size_t)p * (CH * HIDN * 3);
    float* outp = out + (size_t)bid * CH;

    for (int q = 0; q < 16; ++q) {
      const int c0 = wid * 64 + q * 4;
      float l1[4] = {0.f, 0.f, 0.f, 0.f};
      float l3[4] = {0.f, 0.f, 0.f, 0.f};

      for (int h4 = 0; h4 < HIDN; h4 += 4) {
        float h1v[4], h3a[4], h3b[4], h3c[4];
        #pragma unroll
        for (int u = 0; u < 4; ++u) {
          const int hh = h4 + u;
          h1v[u] = bf2f(h1_s[8 + hh * HROW + s]);
          h3a[u] = bf2f(h3_s[7 + hh * HROW + s]);
          h3b[u] = bf2f(h3_s[8 + hh * HROW + s]);
          h3c[u] = bf2f(h3_s[9 + hh * HROW + s]);
        }
        #pragma unroll
        for (int j = 0; j < 4; ++j) {
          const int c = c0 + j;
          const float4 wv  = *(const float4*)&w1b_p[c * HIDN + h4];
          const float* w3  = &w3b_p[(size_t)(c * HIDN + h4) * 3];
          const float4 w30 = *(const float4*)w3;
          const float4 w31 = *(const float4*)(w3 + 4);
          const float4 w32 = *(const float4*)(w3 + 8);
          float ww[12];
          ww[0]=w30.x; ww[1]=w30.y; ww[2]=w30.z; ww[3]=w30.w;
          ww[4]=w31.x; ww[5]=w31.y; ww[6]=w31.z; ww[7]=w31.w;
          ww[8]=w32.x; ww[9]=w32.y; ww[10]=w32.z; ww[11]=w32.w;
          l1[j] = fmaf(wv.x, h1v[0], fmaf(wv.y, h1v[1],
                  fmaf(wv.z, h1v[2], fmaf(wv.w, h1v[3], l1[j]))));
          #pragma unroll
          for (int u = 0; u < 4; ++u) {
            l3[j] = fmaf(ww[u * 3], h3a[u],
                    fmaf(ww[u * 3 + 1], h3b[u],
                    fmaf(ww[u * 3 + 2], h3c[u], l3[j])));
          }
        }
      }

      #pragma unroll
      for (int j = 0; j < 4; ++j) {
        const int c = c0 + j;
        const u16* xr = &x_s[8 + c * XROW];
        const float xm2 = bf2f(xr[s - 2]);
        const float xm1 = bf2f(xr[s - 1]);
        const float x0  = bf2f(xr[s]);
        const float xp1 = bf2f(xr[s + 1]);
        const float xp2 = bf2f(xr[s + 2]);
        const float NI = -INFINITY;
        const float mx3 = fmaxf(x0, fmaxf(s >= 1 ? xm1 : NI, s <= 62 ? xp1 : NI));
        const float mx5 = fmaxf(mx3, fmaxf(s >= 2 ? xm2 : NI, s <= 61 ? xp2 : NI));
        const float av3 = (xm1 + x0 + xp1) * (1.f / 3.f);
        const float av5 = (xm2 + xm1 + x0 + xp1 + xp2) * 0.2f;
        const float sg1 = 1.f / (1.f + __expf(-l1[j]));
        const float sg3 = 1.f / (1.f + __expf(-l3[j]));
        float feat = (av3 + mx3) * sg1 + (av5 + mx5) * sg3;
        #pragma unroll
        for (int off = 32; off >= 1; off >>= 1)
          feat = fmaxf(feat, __shfl_xor(feat, off));
        if (lane == 0) outp[c] = feat;
      }
    }
  }
}

extern "C" void kernel_launch(void* const* d_in, const int* in_sizes, int n_in,
                              void* d_out, int out_size, void* d_ws, size_t ws_size,
                              hipStream_t stream) {
  (void)in_sizes; (void)n_in; (void)out_size;
  const float* x   = (const float*)d_in[0];
  const float* w1a = (const float*)d_in[1];
  const float* w1b = (const float*)d_in[2];
  const float* w3a = (const float*)d_in[3];
  const float* w3b = (const float*)d_in[4];
  float* out = (float*)d_out;

  const size_t WS_NEED = 2621440ull * 2ull;  // 5 MB of bf16 weights
  if (ws_size >= WS_NEED) {
    u16* wsb = (u16*)d_ws;
    cvt_tap<<<1024, 256, 0, stream>>>(w1a, wsb,           3);  // W1A [p][t][h][c]
    cvt_tap<<<1024, 256, 0, stream>>>(w3a, wsb + 786432,  3);  // W3A [p][t][h][c]
    cvt_tap<<<1024, 256, 0, stream>>>(w1b, wsb + 1572864, 1);  // W1B [p][c][h]
    cvt_tap<<<1024, 256, 0, stream>>>(w3b, wsb + 1835008, 3);  // W3B [p][t][c][h]
    tfa_mfma<<<PARTS * NB, 256, 0, stream>>>(x, wsb, out);
  } else {
    tfa_kernel<<<PARTS * NB, 256, 0, stream>>>(x, w1a, w1b, w3a, w3b, out);
  }
}

// Round 7
// 222.483 us; speedup vs baseline: 1.4186x; 1.4186x over previous
//
#include <hip/hip_runtime.h>
#include <hip/hip_bf16.h>

#define PARTS 16
#define NB 128
#define CH 256
#define SL 64
#define HIDN 64

typedef unsigned short u16;
typedef unsigned int u32;
typedef unsigned short ushort8 __attribute__((ext_vector_type(8)));
typedef unsigned short ushort4v __attribute__((ext_vector_type(4)));
typedef __attribute__((ext_vector_type(8))) short short8v;
typedef __attribute__((ext_vector_type(4))) float f32x4;

__device__ __forceinline__ float bf2f(u16 u) {
  union { unsigned u; float f; } t; t.u = ((unsigned)u) << 16; return t.f;
}
__device__ __forceinline__ u16 f2bf(float f) {
  union { float f; unsigned u; } t; t.f = f;
  unsigned u = t.u;
  u += 0x7FFFu + ((u >> 16) & 1u);
  return (u16)(u >> 16);
}
// packed pair convert: low16 = bf16(a), high16 = bf16(b) -> v_cvt_pk_bf16_f32
__device__ __forceinline__ unsigned pk2bf(float a, float b) {
  float2 f; f.x = a; f.y = b;
  union { __hip_bfloat162 h; unsigned u; } cv;
  cv.h = __float22bfloat162_rn(f);
  return cv.u;
}

// ===================== weight conversion prepass =====================
// out[p][t][x] = bf16(in[p][x][t]);  NX = 16384 fixed, NT = 3 or 1.
__global__ void cvt_tap(const float* __restrict__ in, u16* __restrict__ out, int NT) {
  const int i = blockIdx.x * 256 + threadIdx.x;   // p*16384 + x, exact grid
  const int p = i >> 14, xid = i & 16383;
  const float* src = in + (size_t)i * NT;
  for (int t = 0; t < NT; ++t)
    out[(size_t)(p * NT + t) * 16384 + xid] = f2bf(src[t]);
}

// ===================== MFMA main kernel =====================
// Round-3 wave split (phase A: waves split h; phase B: waves split c) —
// minimal per-wave VMEM (round-6 showed 4x per-wave loads = 2.4x regression).
// LDS cut to exactly 40960 B -> 4 blocks/CU -> 16 waves/CU (vs r3's 12):
//  * XT[s][c]: 64 rows x 256 cols bf16, XOR-swizzled, NO pad rows. Conv-tap
//    and pool edge rows handled by per-lane clamp + cndmask-zero.
//  * ht[s][h]: ONE 64x64 buffer, time-multiplexed: phase A writes H1 and
//    keeps H3 packed in 8 VGPRs; B1 computes branch-1 gates; barrier;
//    H3 overwrites ht; barrier; B3 + epilogue.
__device__ __forceinline__ int xsw(int r, int c) { return (r * 256 + c) ^ ((r & 7) << 3); }
__device__ __forceinline__ int hsw(int r, int c) { return (r * 64 + c) ^ ((r & 7) << 3); }

// __launch_bounds__(256, 4): cap 128 VGPR under both readings of arg2
// (r4/r5 ambiguity neutral). LDS 40960 -> 4 blocks/CU.
__global__ __launch_bounds__(256, 4) void tfa_mfma(
    const float* __restrict__ x,
    const u16* __restrict__ wsb,
    float* __restrict__ out)
{
  const u16* W1A = wsb;                 // [p][t][h][c]  786432
  const u16* W3A = wsb + 786432;        // [p][t][h][c]  786432
  const u16* W1B = wsb + 1572864;       // [p][c][h]     262144
  const u16* W3B = wsb + 1835008;       // [p][t][c][h]  786432

  __shared__ __attribute__((aligned(16))) u16 xt[64 * 256];   // 32768 B
  __shared__ __attribute__((aligned(16))) u16 ht[64 * 64];    //  8192 B

  const int tid = threadIdx.x;
  const int bid = blockIdx.x;          // p*NB + n
  const int p = bid >> 7;
  const int lane = tid & 63;
  const int w = tid >> 6;              // wave id 0..3

  // ---- stage x -> XT (transposed, bf16, swizzled); lane = s, wave covers 64 c ----
  {
    const float* xb = x + (size_t)bid * (CH * SL);
    const int s = lane;
    #pragma unroll
    for (int j = 0; j < 8; ++j) {
      const int c0 = w * 64 + j * 8;
      union { ushort8 v; unsigned u[4]; } ov;
      #pragma unroll
      for (int k = 0; k < 4; ++k) {
        const float fa = xb[(c0 + 2 * k) * 64 + s];
        const float fb = xb[(c0 + 2 * k + 1) * 64 + s];
        ov.u[k] = pk2bf(fa, fb);
      }
      *(ushort8*)&xt[xsw(s, c0)] = ov.v;
    }
  }
  __syncthreads();

  const int cm = lane & 15;            // m/n fragment index (hm in phase A)
  const int kg = lane >> 4;            // k-group

  // ---- phase A: conv1 both branches; wave owns h-tile [w*16, w*16+16) ----
  u32 H3pk[4][2];                      // branch-3 hidden, packed bf16 (kept in regs)
  {
    const int h = w * 16 + cm;
    f32x4 acc1[4], acc3[4];
    #pragma unroll
    for (int nt = 0; nt < 4; ++nt) { acc1[nt] = (f32x4)0.f; acc3[nt] = (f32x4)0.f; }

    #pragma unroll 2
    for (int ks = 0; ks < 8; ++ks) {
      const int kc = ks * 32 + kg * 8;
      short8v a1[3], a3[3];
      #pragma unroll
      for (int t = 0; t < 3; ++t) {
        a1[t] = *(const short8v*)&W1A[(size_t)((p * 3 + t) * 64 + h) * 256 + kc];
        a3[t] = *(const short8v*)&W3A[(size_t)((p * 3 + t) * 64 + h) * 256 + kc];
      }
      #pragma unroll
      for (int nt = 0; nt < 4; ++nt) {
        const int s = nt * 16 + cm;    // B-frag n index = lane&15
        #pragma unroll
        for (int t = 0; t < 3; ++t) {
          const int r = s + t - 1;                   // tap row, may be -1 or 64
          const bool oob = (unsigned)r > 63u;
          const short8v bb = *(const short8v*)&xt[xsw(oob ? s : r, kc)];
          const short8v b = oob ? (short8v)(short)0 : bb;   // x pad = 0
          acc1[nt] = __builtin_amdgcn_mfma_f32_16x16x32_bf16(a1[t], b, acc1[nt], 0, 0, 0);
          acc3[nt] = __builtin_amdgcn_mfma_f32_16x16x32_bf16(a3[t], b, acc3[nt], 0, 0, 0);
        }
      }
    }

    // epilogue: LeakyReLU; H1 -> ht (row = s, col = h); H3 -> registers
    const int hc = w * 16 + kg * 4;
    #pragma unroll
    for (int nt = 0; nt < 4; ++nt) {
      const int s = nt * 16 + cm;
      float v1[4], v3[4];
      #pragma unroll
      for (int q = 0; q < 4; ++q) {
        const float a = acc1[nt][q]; v1[q] = a >= 0.f ? a : 0.01f * a;
        const float bq = acc3[nt][q]; v3[q] = bq >= 0.f ? bq : 0.01f * bq;
      }
      union { ushort4v v; u32 u[2]; } o1;
      o1.u[0] = pk2bf(v1[0], v1[1]); o1.u[1] = pk2bf(v1[2], v1[3]);
      *(ushort4v*)&ht[hsw(s, hc)] = o1.v;
      H3pk[nt][0] = pk2bf(v3[0], v3[1]); H3pk[nt][1] = pk2bf(v3[2], v3[3]);
    }
  }
  __syncthreads();

  // ---- phase B1: branch-1 conv2 (k1) -> gates g1, all 4 mt ----
  u32 g1p[4][4][2];                    // [mt][nt][pair] packed sigmoid gates
  #pragma unroll
  for (int half = 0; half < 2; ++half) {
    f32x4 acc[2][4];
    #pragma unroll
    for (int mt = 0; mt < 2; ++mt)
      #pragma unroll
      for (int nt = 0; nt < 4; ++nt) acc[mt][nt] = (f32x4)0.f;

    #pragma unroll
    for (int ks = 0; ks < 2; ++ks) {
      const int kh = ks * 32 + kg * 8;
      short8v a[2];
      #pragma unroll
      for (int mt = 0; mt < 2; ++mt) {
        const int c = w * 64 + (half * 2 + mt) * 16 + cm;
        a[mt] = *(const short8v*)&W1B[((size_t)p * 256 + c) * 64 + kh];
      }
      #pragma unroll
      for (int nt = 0; nt < 4; ++nt) {
        const int s = nt * 16 + cm;
        const short8v b = *(const short8v*)&ht[hsw(s, kh)];   // no shift, no OOB
        #pragma unroll
        for (int mt = 0; mt < 2; ++mt)
          acc[mt][nt] = __builtin_amdgcn_mfma_f32_16x16x32_bf16(a[mt], b, acc[mt][nt], 0, 0, 0);
      }
    }
    #pragma unroll
    for (int mt = 0; mt < 2; ++mt)
      #pragma unroll
      for (int nt = 0; nt < 4; ++nt) {
        #pragma unroll
        for (int j = 0; j < 2; ++j) {
          const float ga = 1.f / (1.f + __expf(-acc[mt][nt][2 * j]));
          const float gb = 1.f / (1.f + __expf(-acc[mt][nt][2 * j + 1]));
          g1p[half * 2 + mt][nt][j] = pk2bf(ga, gb);
        }
      }
  }
  __syncthreads();                     // all waves done reading H1

  // ---- overwrite ht with H3 ----
  {
    const int hc = w * 16 + kg * 4;
    #pragma unroll
    for (int nt = 0; nt < 4; ++nt) {
      const int s = nt * 16 + cm;
      union { ushort4v v; u32 u[2]; } o3;
      o3.u[0] = H3pk[nt][0]; o3.u[1] = H3pk[nt][1];
      *(ushort4v*)&ht[hsw(s, hc)] = o3.v;
    }
  }
  __syncthreads();

  // ---- phase B3: branch-3 conv2 (k3) + full epilogue, in mt-halves ----
  #pragma unroll 1
  for (int half = 0; half < 2; ++half) {
    f32x4 acc[2][4];
    #pragma unroll
    for (int mt = 0; mt < 2; ++mt)
      #pragma unroll
      for (int nt = 0; nt < 4; ++nt) acc[mt][nt] = (f32x4)0.f;

    #pragma unroll
    for (int ks = 0; ks < 2; ++ks) {
      const int kh = ks * 32 + kg * 8;
      #pragma unroll
      for (int t = 0; t < 3; ++t) {
        short8v a[2];
        #pragma unroll
        for (int mt = 0; mt < 2; ++mt) {
          const int c = w * 64 + (half * 2 + mt) * 16 + cm;
          a[mt] = *(const short8v*)&W3B[(size_t)((p * 3 + t) * 256 + c) * 64 + kh];
        }
        #pragma unroll
        for (int nt = 0; nt < 4; ++nt) {
          const int s = nt * 16 + cm;
          const int r = s + t - 1;                   // tap row, may be -1 or 64
          const bool oob = (unsigned)r > 63u;
          const short8v bb = *(const short8v*)&ht[hsw(oob ? s : r, kh)];
          const short8v b = oob ? (short8v)(short)0 : bb;   // H3 pad = 0
          #pragma unroll
          for (int mt = 0; mt < 2; ++mt)
            acc[mt][nt] = __builtin_amdgcn_mfma_f32_16x16x32_bf16(a[mt], b, acc[mt][nt], 0, 0, 0);
        }
      }
    }

    // epilogue: pools from XT (clamped rows), gates, fused max over s
    #pragma unroll
    for (int mt = 0; mt < 2; ++mt) {
      const int c4 = w * 64 + (half * 2 + mt) * 16 + kg * 4;  // D rows: 4 consecutive c
      float fmx0 = -INFINITY, fmx1 = -INFINITY, fmx2 = -INFINITY, fmx3 = -INFINITY;
      #pragma unroll
      for (int nt = 0; nt < 4; ++nt) {
        const int sg = nt * 16 + cm;               // D col: global s
        const int rm2 = sg >= 2 ? sg - 2 : 0;
        const int rm1 = sg >= 1 ? sg - 1 : 0;
        const int rp1 = sg <= 62 ? sg + 1 : 63;
        const int rp2 = sg <= 61 ? sg + 2 : 63;
        const ushort4v vm2 = *(const ushort4v*)&xt[xsw(rm2, c4)];
        const ushort4v vm1 = *(const ushort4v*)&xt[xsw(rm1, c4)];
        const ushort4v v0  = *(const ushort4v*)&xt[xsw(sg,  c4)];
        const ushort4v vp1 = *(const ushort4v*)&xt[xsw(rp1, c4)];
        const ushort4v vp2 = *(const ushort4v*)&xt[xsw(rp2, c4)];
        const float NI = -INFINITY;
        float ft[4];
        #pragma unroll
        for (int q = 0; q < 4; ++q) {
          const float xm2r = bf2f(vm2[q]), xm1r = bf2f(vm1[q]), x0 = bf2f(v0[q]);
          const float xp1r = bf2f(vp1[q]), xp2r = bf2f(vp2[q]);
          // avg: pad counts as 0 (count_include_pad); max: pad excluded (NI)
          const float am2 = sg >= 2 ? xm2r : 0.f;
          const float am1 = sg >= 1 ? xm1r : 0.f;
          const float ap1 = sg <= 62 ? xp1r : 0.f;
          const float ap2 = sg <= 61 ? xp2r : 0.f;
          const float mx3 = fmaxf(x0, fmaxf(sg >= 1 ? xm1r : NI, sg <= 62 ? xp1r : NI));
          const float mx5 = fmaxf(mx3, fmaxf(sg >= 2 ? xm2r : NI, sg <= 61 ? xp2r : NI));
          const float av3 = (am1 + x0 + ap1) * (1.f / 3.f);
          const float av5 = (am2 + am1 + x0 + ap1 + ap2) * 0.2f;
          const float g1 = bf2f((u16)(g1p[half * 2 + mt][nt][q >> 1] >> ((q & 1) * 16)));
          const float g3 = 1.f / (1.f + __expf(-acc[mt][nt][q]));
          ft[q] = (av3 + mx3) * g1 + (av5 + mx5) * g3;
        }
        fmx0 = fmaxf(fmx0, ft[0]); fmx1 = fmaxf(fmx1, ft[1]);
        fmx2 = fmaxf(fmx2, ft[2]); fmx3 = fmaxf(fmx3, ft[3]);
      }
      // reduce max across the 16 lanes of each row-group (xor bits 0..3)
      #pragma unroll
      for (int off = 1; off < 16; off <<= 1) {
        fmx0 = fmaxf(fmx0, __shfl_xor(fmx0, off));
        fmx1 = fmaxf(fmx1, __shfl_xor(fmx1, off));
        fmx2 = fmaxf(fmx2, __shfl_xor(fmx2, off));
        fmx3 = fmaxf(fmx3, __shfl_xor(fmx3, off));
      }
      if (cm == 0) {
        float4 o; o.x = fmx0; o.y = fmx1; o.z = fmx2; o.w = fmx3;
        *(float4*)&out[(size_t)bid * 256 + c4] = o;
      }
    }
  }
}

// ===================== fallback vector kernel (round-1, correct) =====================
#define XROW 72
#define HROW 72

__global__ __launch_bounds__(256, 2) void tfa_kernel(
    const float* __restrict__ x,
    const float* __restrict__ w1a,
    const float* __restrict__ w1b,
    const float* __restrict__ w3a,
    const float* __restrict__ w3b,
    float* __restrict__ out)
{
  __shared__ __attribute__((aligned(16))) u16 x_s[8 + CH * XROW];
  __shared__ __attribute__((aligned(16))) u16 h1_s[8 + HIDN * HROW];
  __shared__ __attribute__((aligned(16))) u16 h3_s[8 + HIDN * HROW];

  const int tid = threadIdx.x;
  const int bid = blockIdx.x;
  const int p = bid >> 7;

  {
    const ushort8 z = {0, 0, 0, 0, 0, 0, 0, 0};
    for (int i = tid; i < 257; i += 256) {
      u16* dst = (i == 0) ? &x_s[0] : &x_s[8 + (i - 1) * XROW + 64];
      *(ushort8*)dst = z;
    }
    if (tid < 65) {
      u16* d1 = (tid == 0) ? &h1_s[0] : &h1_s[8 + (tid - 1) * HROW + 64];
      *(ushort8*)d1 = z;
      u16* d3 = (tid == 0) ? &h3_s[0] : &h3_s[8 + (tid - 1) * HROW + 64];
      *(ushort8*)d3 = z;
    }
  }

  const float* xblk = x + (size_t)bid * (CH * SL);
  #pragma unroll
  for (int j = 0; j < 16; ++j) {
    const int g = tid + 256 * j;
    const float4 v = ((const float4*)xblk)[g];
    const int c = g >> 4, s4 = g & 15;
    ushort4v o;
    o[0] = f2bf(v.x); o[1] = f2bf(v.y); o[2] = f2bf(v.z); o[3] = f2bf(v.w);
    *(ushort4v*)&x_s[8 + c * XROW + s4 * 4] = o;
  }
  __syncthreads();

  {
    const int h = tid >> 2;
    const int sg = tid & 3;
    const int sb = sg << 4;
    float acc1[16], acc3[16];
    #pragma unroll
    for (int i = 0; i < 16; ++i) { acc1[i] = 0.f; acc3[i] = 0.f; }

    const float* w1a_p = w1a + ((size_t)p * HIDN + h) * (CH * 3);
    const float* w3a_p = w3a + ((size_t)p * HIDN + h) * (CH * 3);

    for (int c4 = 0; c4 < CH; c4 += 4) {
      const float4 a0v = *(const float4*)&w1a_p[c4 * 3];
      const float4 a1v = *(const float4*)&w1a_p[c4 * 3 + 4];
      const float4 a2v = *(const float4*)&w1a_p[c4 * 3 + 8];
      const float4 b0v = *(const float4*)&w3a_p[c4 * 3];
      const float4 b1v = *(const float4*)&w3a_p[c4 * 3 + 4];
      const float4 b2v = *(const float4*)&w3a_p[c4 * 3 + 8];
      float wa[12], wb[12];
      wa[0]=a0v.x; wa[1]=a0v.y; wa[2]=a0v.z; wa[3]=a0v.w;
      wa[4]=a1v.x; wa[5]=a1v.y; wa[6]=a1v.z; wa[7]=a1v.w;
      wa[8]=a2v.x; wa[9]=a2v.y; wa[10]=a2v.z; wa[11]=a2v.w;
      wb[0]=b0v.x; wb[1]=b0v.y; wb[2]=b0v.z; wb[3]=b0v.w;
      wb[4]=b1v.x; wb[5]=b1v.y; wb[6]=b1v.z; wb[7]=b1v.w;
      wb[8]=b2v.x; wb[9]=b2v.y; wb[10]=b2v.z; wb[11]=b2v.w;

      #pragma unroll
      for (int cc = 0; cc < 4; ++cc) {
        const int c = c4 + cc;
        const ushort8 w0v = *(const ushort8*)&x_s[c * XROW + sb];
        const ushort8 w1v = *(const ushort8*)&x_s[c * XROW + sb + 8];
        const ushort8 w2v = *(const ushort8*)&x_s[c * XROW + sb + 16];
        const ushort8 w3v = *(const ushort8*)&x_s[c * XROW + sb + 24];
        float xf[19];
        xf[0] = bf2f(w0v[7]);
        #pragma unroll
        for (int d = 0; d < 8; ++d) xf[1 + d] = bf2f(w1v[d]);
        #pragma unroll
        for (int d = 0; d < 8; ++d) xf[9 + d] = bf2f(w2v[d]);
        xf[17] = bf2f(w3v[0]);
        xf[18] = bf2f(w3v[1]);

        const float a0 = wa[cc * 3], a1 = wa[cc * 3 + 1], a2 = wa[cc * 3 + 2];
        const float b0 = wb[cc * 3], b1 = wb[cc * 3 + 1], b2 = wb[cc * 3 + 2];
        #pragma unroll
        for (int i = 0; i < 16; ++i) {
          const float xm = xf[i], x0 = xf[i + 1], xp = xf[i + 2];
          acc1[i] = fmaf(a0, xm, fmaf(a1, x0, fmaf(a2, xp, acc1[i])));
          acc3[i] = fmaf(b0, xm, fmaf(b1, x0, fmaf(b2, xp, acc3[i])));
        }
      }
    }

    ushort8 o1a, o1b, o3a, o3b;
    #pragma unroll
    for (int i = 0; i < 8; ++i) {
      float v1 = acc1[i];     v1 = v1 >= 0.f ? v1 : 0.01f * v1;
      float v3 = acc3[i];     v3 = v3 >= 0.f ? v3 : 0.01f * v3;
      o1a[i] = f2bf(v1); o3a[i] = f2bf(v3);
      float u1 = acc1[i + 8]; u1 = u1 >= 0.f ? u1 : 0.01f * u1;
      float u3 = acc3[i + 8]; u3 = u3 >= 0.f ? u3 : 0.01f * u3;
      o1b[i] = f2bf(u1); o3b[i] = f2bf(u3);
    }
    *(ushort8*)&h1_s[8 + h * HROW + sb]     = o1a;
    *(ushort8*)&h1_s[8 + h * HROW + sb + 8] = o1b;
    *(ushort8*)&h3_s[8 + h * HROW + sb]     = o3a;
    *(ushort8*)&h3_s[8 + h * HROW + sb + 8] = o3b;
  }
  __syncthreads();

  {
    const int lane = tid & 63;
    const int wid = __builtin_amdgcn_readfirstlane(tid >> 6);
    const int s = lane;
    const float* w1b_p = w1b + (size_t)p * (CH * HIDN);
    const float* w3b_p = w3b + (size_t)p * (CH * HIDN * 3);
    float* outp = out + (size_t)bid * CH;

    for (int q = 0; q < 16; ++q) {
      const int c0 = wid * 64 + q * 4;
      float l1[4] = {0.f, 0.f, 0.f, 0.f};
      float l3[4] = {0.f, 0.f, 0.f, 0.f};

      for (int h4 = 0; h4 < HIDN; h4 += 4) {
        float h1v[4], h3a[4], h3b[4], h3c[4];
        #pragma unroll
        for (int u = 0; u < 4; ++u) {
          const int hh = h4 + u;
          h1v[u] = bf2f(h1_s[8 + hh * HROW + s]);
          h3a[u] = bf2f(h3_s[7 + hh * HROW + s]);
          h3b[u] = bf2f(h3_s[8 + hh * HROW + s]);
          h3c[u] = bf2f(h3_s[9 + hh * HROW + s]);
        }
        #pragma unroll
        for (int j = 0; j < 4; ++j) {
          const int c = c0 + j;
          const float4 wv  = *(const float4*)&w1b_p[c * HIDN + h4];
          const float* w3  = &w3b_p[(size_t)(c * HIDN + h4) * 3];
          const float4 w30 = *(const float4*)w3;
          const float4 w31 = *(const float4*)(w3 + 4);
          const float4 w32 = *(const float4*)(w3 + 8);
          float ww[12];
          ww[0]=w30.x; ww[1]=w30.y; ww[2]=w30.z; ww[3]=w30.w;
          ww[4]=w31.x; ww[5]=w31.y; ww[6]=w31.z; ww[7]=w31.w;
          ww[8]=w32.x; ww[9]=w32.y; ww[10]=w32.z; ww[11]=w32.w;
          l1[j] = fmaf(wv.x, h1v[0], fmaf(wv.y, h1v[1],
                  fmaf(wv.z, h1v[2], fmaf(wv.w, h1v[3], l1[j]))));
          #pragma unroll
          for (int u = 0; u < 4; ++u) {
            l3[j] = fmaf(ww[u * 3], h3a[u],
                    fmaf(ww[u * 3 + 1], h3b[u],
                    fmaf(ww[u * 3 + 2], h3c[u], l3[j])));
          }
        }
      }

      #pragma unroll
      for (int j = 0; j < 4; ++j) {
        const int c = c0 + j;
        const u16* xr = &x_s[8 + c * XROW];
        const float xm2 = bf2f(xr[s - 2]);
        const float xm1 = bf2f(xr[s - 1]);
        const float x0  = bf2f(xr[s]);
        const float xp1 = bf2f(xr[s + 1]);
        const float xp2 = bf2f(xr[s + 2]);
        const float NI = -INFINITY;
        const float mx3 = fmaxf(x0, fmaxf(s >= 1 ? xm1 : NI, s <= 62 ? xp1 : NI));
        const float mx5 = fmaxf(mx3, fmaxf(s >= 2 ? xm2 : NI, s <= 61 ? xp2 : NI));
        const float av3 = (xm1 + x0 + xp1) * (1.f / 3.f);
        const float av5 = (xm2 + xm1 + x0 + xp1 + xp2) * 0.2f;
        const float sg1 = 1.f / (1.f + __expf(-l1[j]));
        const float sg3 = 1.f / (1.f + __expf(-l3[j]));
        float feat = (av3 + mx3) * sg1 + (av5 + mx5) * sg3;
        #pragma unroll
        for (int off = 32; off >= 1; off >>= 1)
          feat = fmaxf(feat, __shfl_xor(feat, off));
        if (lane == 0) outp[c] = feat;
      }
    }
  }
}

extern "C" void kernel_launch(void* const* d_in, const int* in_sizes, int n_in,
                              void* d_out, int out_size, void* d_ws, size_t ws_size,
                              hipStream_t stream) {
  (void)in_sizes; (void)n_in; (void)out_size;
  const float* x   = (const float*)d_in[0];
  const float* w1a = (const float*)d_in[1];
  const float* w1b = (const float*)d_in[2];
  const float* w3a = (const float*)d_in[3];
  const float* w3b = (const float*)d_in[4];
  float* out = (float*)d_out;

  const size_t WS_NEED = 2621440ull * 2ull;  // 5 MB of bf16 weights
  if (ws_size >= WS_NEED) {
    u16* wsb = (u16*)d_ws;
    cvt_tap<<<1024, 256, 0, stream>>>(w1a, wsb,           3);  // W1A [p][t][h][c]
    cvt_tap<<<1024, 256, 0, stream>>>(w3a, wsb + 786432,  3);  // W3A [p][t][h][c]
    cvt_tap<<<1024, 256, 0, stream>>>(w1b, wsb + 1572864, 1);  // W1B [p][c][h]
    cvt_tap<<<1024, 256, 0, stream>>>(w3b, wsb + 1835008, 3);  // W3B [p][t][c][h]
    tfa_mfma<<<PARTS * NB, 256, 0, stream>>>(x, wsb, out);
  } else {
    tfa_kernel<<<PARTS * NB, 256, 0, stream>>>(x, w1a, w1b, w3a, w3b, out);
  }
}

// Round 8
// 136.933 us; speedup vs baseline: 2.3049x; 1.6247x over previous
//
#include <hip/hip_runtime.h>
#include <hip/hip_bf16.h>

#define PARTS 16
#define NB 128
#define CH 256
#define SL 64
#define HIDN 64

typedef unsigned short u16;
typedef unsigned int u32;
typedef unsigned short ushort8 __attribute__((ext_vector_type(8)));
typedef unsigned short ushort4v __attribute__((ext_vector_type(4)));
typedef __attribute__((ext_vector_type(8))) short short8v;
typedef __attribute__((ext_vector_type(4))) float f32x4;

__device__ __forceinline__ float bf2f(u16 u) {
  union { unsigned u; float f; } t; t.u = ((unsigned)u) << 16; return t.f;
}
__device__ __forceinline__ u16 f2bf(float f) {
  union { float f; unsigned u; } t; t.f = f;
  unsigned u = t.u;
  u += 0x7FFFu + ((u >> 16) & 1u);
  return (u16)(u >> 16);
}
// packed pair convert: low16 = bf16(a), high16 = bf16(b) -> v_cvt_pk_bf16_f32
__device__ __forceinline__ unsigned pk2bf(float a, float b) {
  float2 f; f.x = a; f.y = b;
  union { __hip_bfloat162 h; unsigned u; } cv;
  cv.h = __float22bfloat162_rn(f);
  return cv.u;
}

// ===================== weight conversion prepass =====================
// out[p][t][x] = bf16(in[p][x][t]);  NX = 16384 fixed, NT = 3 or 1.
__global__ void cvt_tap(const float* __restrict__ in, u16* __restrict__ out, int NT) {
  const int i = blockIdx.x * 256 + threadIdx.x;   // p*16384 + x, exact grid
  const int p = i >> 14, xid = i & 16383;
  const float* src = in + (size_t)i * NT;
  for (int t = 0; t < NT; ++t)
    out[(size_t)(p * NT + t) * 16384 + xid] = f2bf(src[t]);
}

// ===================== MFMA main kernel =====================
// Round-3 wave split (phase A: waves split h; phase B: waves split c) —
// minimal per-wave VMEM (round-6 showed 4x per-wave loads = 2.4x regression).
// LDS cut to exactly 40960 B -> 4 blocks/CU -> 16 waves/CU (vs r3's 12):
//  * XT[s][c]: 64 rows x 256 cols bf16, XOR-swizzled, NO pad rows. Conv-tap
//    and pool edge rows handled by per-lane clamp + cndmask-zero.
//  * ht[s][h]: ONE 64x64 buffer, time-multiplexed: phase A writes H1 and
//    keeps H3 packed in 8 VGPRs; B1 computes branch-1 gates; barrier;
//    H3 overwrites ht; barrier; B3 + epilogue.
__device__ __forceinline__ int xsw(int r, int c) { return (r * 256 + c) ^ ((r & 7) << 3); }
__device__ __forceinline__ int hsw(int r, int c) { return (r * 64 + c) ^ ((r & 7) << 3); }

// __launch_bounds__(256, 2): empirical model from r2-r7 calibration — this
// compiler's effective VGPR cap = 256/arg2:
//   (512,6)->40, (512,3)->80, (256,4)->64, (256,2)-> cap 128 (r3 used 84).
// Cap 128 = exactly 4 waves/EU, matching the LDS limit (40960 B -> 4
// blocks/CU -> 16 waves/CU). No-spill falsifier: WRITE_SIZE ~2 MB.
__global__ __launch_bounds__(256, 2) void tfa_mfma(
    const float* __restrict__ x,
    const u16* __restrict__ wsb,
    float* __restrict__ out)
{
  const u16* W1A = wsb;                 // [p][t][h][c]  786432
  const u16* W3A = wsb + 786432;        // [p][t][h][c]  786432
  const u16* W1B = wsb + 1572864;       // [p][c][h]     262144
  const u16* W3B = wsb + 1835008;       // [p][t][c][h]  786432

  __shared__ __attribute__((aligned(16))) u16 xt[64 * 256];   // 32768 B
  __shared__ __attribute__((aligned(16))) u16 ht[64 * 64];    //  8192 B

  const int tid = threadIdx.x;
  const int bid = blockIdx.x;          // p*NB + n
  const int p = bid >> 7;
  const int lane = tid & 63;
  const int w = tid >> 6;              // wave id 0..3

  // ---- stage x -> XT (transposed, bf16, swizzled); lane = s, wave covers 64 c ----
  {
    const float* xb = x + (size_t)bid * (CH * SL);
    const int s = lane;
    #pragma unroll
    for (int j = 0; j < 8; ++j) {
      const int c0 = w * 64 + j * 8;
      union { ushort8 v; unsigned u[4]; } ov;
      #pragma unroll
      for (int k = 0; k < 4; ++k) {
        const float fa = xb[(c0 + 2 * k) * 64 + s];
        const float fb = xb[(c0 + 2 * k + 1) * 64 + s];
        ov.u[k] = pk2bf(fa, fb);
      }
      *(ushort8*)&xt[xsw(s, c0)] = ov.v;
    }
  }
  __syncthreads();

  const int cm = lane & 15;            // m/n fragment index (hm in phase A)
  const int kg = lane >> 4;            // k-group

  // ---- phase A: conv1 both branches; wave owns h-tile [w*16, w*16+16) ----
  u32 H3pk[4][2];                      // branch-3 hidden, packed bf16 (kept in regs)
  {
    const int h = w * 16 + cm;
    f32x4 acc1[4], acc3[4];
    #pragma unroll
    for (int nt = 0; nt < 4; ++nt) { acc1[nt] = (f32x4)0.f; acc3[nt] = (f32x4)0.f; }

    #pragma unroll 2
    for (int ks = 0; ks < 8; ++ks) {
      const int kc = ks * 32 + kg * 8;
      short8v a1[3], a3[3];
      #pragma unroll
      for (int t = 0; t < 3; ++t) {
        a1[t] = *(const short8v*)&W1A[(size_t)((p * 3 + t) * 64 + h) * 256 + kc];
        a3[t] = *(const short8v*)&W3A[(size_t)((p * 3 + t) * 64 + h) * 256 + kc];
      }
      #pragma unroll
      for (int nt = 0; nt < 4; ++nt) {
        const int s = nt * 16 + cm;    // B-frag n index = lane&15
        #pragma unroll
        for (int t = 0; t < 3; ++t) {
          const int r = s + t - 1;                   // tap row, may be -1 or 64
          const bool oob = (unsigned)r > 63u;
          const short8v bb = *(const short8v*)&xt[xsw(oob ? s : r, kc)];
          const short8v b = oob ? (short8v)(short)0 : bb;   // x pad = 0
          acc1[nt] = __builtin_amdgcn_mfma_f32_16x16x32_bf16(a1[t], b, acc1[nt], 0, 0, 0);
          acc3[nt] = __builtin_amdgcn_mfma_f32_16x16x32_bf16(a3[t], b, acc3[nt], 0, 0, 0);
        }
      }
    }

    // epilogue: LeakyReLU; H1 -> ht (row = s, col = h); H3 -> registers
    const int hc = w * 16 + kg * 4;
    #pragma unroll
    for (int nt = 0; nt < 4; ++nt) {
      const int s = nt * 16 + cm;
      float v1[4], v3[4];
      #pragma unroll
      for (int q = 0; q < 4; ++q) {
        const float a = acc1[nt][q]; v1[q] = a >= 0.f ? a : 0.01f * a;
        const float bq = acc3[nt][q]; v3[q] = bq >= 0.f ? bq : 0.01f * bq;
      }
      union { ushort4v v; u32 u[2]; } o1;
      o1.u[0] = pk2bf(v1[0], v1[1]); o1.u[1] = pk2bf(v1[2], v1[3]);
      *(ushort4v*)&ht[hsw(s, hc)] = o1.v;
      H3pk[nt][0] = pk2bf(v3[0], v3[1]); H3pk[nt][1] = pk2bf(v3[2], v3[3]);
    }
  }
  __syncthreads();

  // ---- phase B1: branch-1 conv2 (k1) -> gates g1, all 4 mt ----
  u32 g1p[4][4][2];                    // [mt][nt][pair] packed sigmoid gates
  #pragma unroll
  for (int half = 0; half < 2; ++half) {
    f32x4 acc[2][4];
    #pragma unroll
    for (int mt = 0; mt < 2; ++mt)
      #pragma unroll
      for (int nt = 0; nt < 4; ++nt) acc[mt][nt] = (f32x4)0.f;

    #pragma unroll
    for (int ks = 0; ks < 2; ++ks) {
      const int kh = ks * 32 + kg * 8;
      short8v a[2];
      #pragma unroll
      for (int mt = 0; mt < 2; ++mt) {
        const int c = w * 64 + (half * 2 + mt) * 16 + cm;
        a[mt] = *(const short8v*)&W1B[((size_t)p * 256 + c) * 64 + kh];
      }
      #pragma unroll
      for (int nt = 0; nt < 4; ++nt) {
        const int s = nt * 16 + cm;
        const short8v b = *(const short8v*)&ht[hsw(s, kh)];   // no shift, no OOB
        #pragma unroll
        for (int mt = 0; mt < 2; ++mt)
          acc[mt][nt] = __builtin_amdgcn_mfma_f32_16x16x32_bf16(a[mt], b, acc[mt][nt], 0, 0, 0);
      }
    }
    #pragma unroll
    for (int mt = 0; mt < 2; ++mt)
      #pragma unroll
      for (int nt = 0; nt < 4; ++nt) {
        #pragma unroll
        for (int j = 0; j < 2; ++j) {
          const float ga = 1.f / (1.f + __expf(-acc[mt][nt][2 * j]));
          const float gb = 1.f / (1.f + __expf(-acc[mt][nt][2 * j + 1]));
          g1p[half * 2 + mt][nt][j] = pk2bf(ga, gb);
        }
      }
  }
  __syncthreads();                     // all waves done reading H1

  // ---- overwrite ht with H3 ----
  {
    const int hc = w * 16 + kg * 4;
    #pragma unroll
    for (int nt = 0; nt < 4; ++nt) {
      const int s = nt * 16 + cm;
      union { ushort4v v; u32 u[2]; } o3;
      o3.u[0] = H3pk[nt][0]; o3.u[1] = H3pk[nt][1];
      *(ushort4v*)&ht[hsw(s, hc)] = o3.v;
    }
  }
  __syncthreads();

  // ---- phase B3: branch-3 conv2 (k3) + full epilogue, in mt-halves ----
  #pragma unroll 1
  for (int half = 0; half < 2; ++half) {
    f32x4 acc[2][4];
    #pragma unroll
    for (int mt = 0; mt < 2; ++mt)
      #pragma unroll
      for (int nt = 0; nt < 4; ++nt) acc[mt][nt] = (f32x4)0.f;

    #pragma unroll
    for (int ks = 0; ks < 2; ++ks) {
      const int kh = ks * 32 + kg * 8;
      #pragma unroll
      for (int t = 0; t < 3; ++t) {
        short8v a[2];
        #pragma unroll
        for (int mt = 0; mt < 2; ++mt) {
          const int c = w * 64 + (half * 2 + mt) * 16 + cm;
          a[mt] = *(const short8v*)&W3B[(size_t)((p * 3 + t) * 256 + c) * 64 + kh];
        }
        #pragma unroll
        for (int nt = 0; nt < 4; ++nt) {
          const int s = nt * 16 + cm;
          const int r = s + t - 1;                   // tap row, may be -1 or 64
          const bool oob = (unsigned)r > 63u;
          const short8v bb = *(const short8v*)&ht[hsw(oob ? s : r, kh)];
          const short8v b = oob ? (short8v)(short)0 : bb;   // H3 pad = 0
          #pragma unroll
          for (int mt = 0; mt < 2; ++mt)
            acc[mt][nt] = __builtin_amdgcn_mfma_f32_16x16x32_bf16(a[mt], b, acc[mt][nt], 0, 0, 0);
        }
      }
    }

    // epilogue: pools from XT (clamped rows), gates, fused max over s
    #pragma unroll
    for (int mt = 0; mt < 2; ++mt) {
      const int c4 = w * 64 + (half * 2 + mt) * 16 + kg * 4;  // D rows: 4 consecutive c
      float fmx0 = -INFINITY, fmx1 = -INFINITY, fmx2 = -INFINITY, fmx3 = -INFINITY;
      #pragma unroll
      for (int nt = 0; nt < 4; ++nt) {
        const int sg = nt * 16 + cm;               // D col: global s
        const int rm2 = sg >= 2 ? sg - 2 : 0;
        const int rm1 = sg >= 1 ? sg - 1 : 0;
        const int rp1 = sg <= 62 ? sg + 1 : 63;
        const int rp2 = sg <= 61 ? sg + 2 : 63;
        const ushort4v vm2 = *(const ushort4v*)&xt[xsw(rm2, c4)];
        const ushort4v vm1 = *(const ushort4v*)&xt[xsw(rm1, c4)];
        const ushort4v v0  = *(const ushort4v*)&xt[xsw(sg,  c4)];
        const ushort4v vp1 = *(const ushort4v*)&xt[xsw(rp1, c4)];
        const ushort4v vp2 = *(const ushort4v*)&xt[xsw(rp2, c4)];
        const float NI = -INFINITY;
        float ft[4];
        #pragma unroll
        for (int q = 0; q < 4; ++q) {
          const float xm2r = bf2f(vm2[q]), xm1r = bf2f(vm1[q]), x0 = bf2f(v0[q]);
          const float xp1r = bf2f(vp1[q]), xp2r = bf2f(vp2[q]);
          // avg: pad counts as 0 (count_include_pad); max: pad excluded (NI)
          const float am2 = sg >= 2 ? xm2r : 0.f;
          const float am1 = sg >= 1 ? xm1r : 0.f;
          const float ap1 = sg <= 62 ? xp1r : 0.f;
          const float ap2 = sg <= 61 ? xp2r : 0.f;
          const float mx3 = fmaxf(x0, fmaxf(sg >= 1 ? xm1r : NI, sg <= 62 ? xp1r : NI));
          const float mx5 = fmaxf(mx3, fmaxf(sg >= 2 ? xm2r : NI, sg <= 61 ? xp2r : NI));
          const float av3 = (am1 + x0 + ap1) * (1.f / 3.f);
          const float av5 = (am2 + am1 + x0 + ap1 + ap2) * 0.2f;
          const float g1 = bf2f((u16)(g1p[half * 2 + mt][nt][q >> 1] >> ((q & 1) * 16)));
          const float g3 = 1.f / (1.f + __expf(-acc[mt][nt][q]));
          ft[q] = (av3 + mx3) * g1 + (av5 + mx5) * g3;
        }
        fmx0 = fmaxf(fmx0, ft[0]); fmx1 = fmaxf(fmx1, ft[1]);
        fmx2 = fmaxf(fmx2, ft[2]); fmx3 = fmaxf(fmx3, ft[3]);
      }
      // reduce max across the 16 lanes of each row-group (xor bits 0..3)
      #pragma unroll
      for (int off = 1; off < 16; off <<= 1) {
        fmx0 = fmaxf(fmx0, __shfl_xor(fmx0, off));
        fmx1 = fmaxf(fmx1, __shfl_xor(fmx1, off));
        fmx2 = fmaxf(fmx2, __shfl_xor(fmx2, off));
        fmx3 = fmaxf(fmx3, __shfl_xor(fmx3, off));
      }
      if (cm == 0) {
        float4 o; o.x = fmx0; o.y = fmx1; o.z = fmx2; o.w = fmx3;
        *(float4*)&out[(size_t)bid * 256 + c4] = o;
      }
    }
  }
}

// ===================== fallback vector kernel (round-1, correct) =====================
#define XROW 72
#define HROW 72

__global__ __launch_bounds__(256, 2) void tfa_kernel(
    const float* __restrict__ x,
    const float* __restrict__ w1a,
    const float* __restrict__ w1b,
    const float* __restrict__ w3a,
    const float* __restrict__ w3b,
    float* __restrict__ out)
{
  __shared__ __attribute__((aligned(16))) u16 x_s[8 + CH * XROW];
  __shared__ __attribute__((aligned(16))) u16 h1_s[8 + HIDN * HROW];
  __shared__ __attribute__((aligned(16))) u16 h3_s[8 + HIDN * HROW];

  const int tid = threadIdx.x;
  const int bid = blockIdx.x;
  const int p = bid >> 7;

  {
    const ushort8 z = {0, 0, 0, 0, 0, 0, 0, 0};
    for (int i = tid; i < 257; i += 256) {
      u16* dst = (i == 0) ? &x_s[0] : &x_s[8 + (i - 1) * XROW + 64];
      *(ushort8*)dst = z;
    }
    if (tid < 65) {
      u16* d1 = (tid == 0) ? &h1_s[0] : &h1_s[8 + (tid - 1) * HROW + 64];
      *(ushort8*)d1 = z;
      u16* d3 = (tid == 0) ? &h3_s[0] : &h3_s[8 + (tid - 1) * HROW + 64];
      *(ushort8*)d3 = z;
    }
  }

  const float* xblk = x + (size_t)bid * (CH * SL);
  #pragma unroll
  for (int j = 0; j < 16; ++j) {
    const int g = tid + 256 * j;
    const float4 v = ((const float4*)xblk)[g];
    const int c = g >> 4, s4 = g & 15;
    ushort4v o;
    o[0] = f2bf(v.x); o[1] = f2bf(v.y); o[2] = f2bf(v.z); o[3] = f2bf(v.w);
    *(ushort4v*)&x_s[8 + c * XROW + s4 * 4] = o;
  }
  __syncthreads();

  {
    const int h = tid >> 2;
    const int sg = tid & 3;
    const int sb = sg << 4;
    float acc1[16], acc3[16];
    #pragma unroll
    for (int i = 0; i < 16; ++i) { acc1[i] = 0.f; acc3[i] = 0.f; }

    const float* w1a_p = w1a + ((size_t)p * HIDN + h) * (CH * 3);
    const float* w3a_p = w3a + ((size_t)p * HIDN + h) * (CH * 3);

    for (int c4 = 0; c4 < CH; c4 += 4) {
      const float4 a0v = *(const float4*)&w1a_p[c4 * 3];
      const float4 a1v = *(const float4*)&w1a_p[c4 * 3 + 4];
      const float4 a2v = *(const float4*)&w1a_p[c4 * 3 + 8];
      const float4 b0v = *(const float4*)&w3a_p[c4 * 3];
      const float4 b1v = *(const float4*)&w3a_p[c4 * 3 + 4];
      const float4 b2v = *(const float4*)&w3a_p[c4 * 3 + 8];
      float wa[12], wb[12];
      wa[0]=a0v.x; wa[1]=a0v.y; wa[2]=a0v.z; wa[3]=a0v.w;
      wa[4]=a1v.x; wa[5]=a1v.y; wa[6]=a1v.z; wa[7]=a1v.w;
      wa[8]=a2v.x; wa[9]=a2v.y; wa[10]=a2v.z; wa[11]=a2v.w;
      wb[0]=b0v.x; wb[1]=b0v.y; wb[2]=b0v.z; wb[3]=b0v.w;
      wb[4]=b1v.x; wb[5]=b1v.y; wb[6]=b1v.z; wb[7]=b1v.w;
      wb[8]=b2v.x; wb[9]=b2v.y; wb[10]=b2v.z; wb[11]=b2v.w;

      #pragma unroll
      for (int cc = 0; cc < 4; ++cc) {
        const int c = c4 + cc;
        const ushort8 w0v = *(const ushort8*)&x_s[c * XROW + sb];
        const ushort8 w1v = *(const ushort8*)&x_s[c * XROW + sb + 8];
        const ushort8 w2v = *(const ushort8*)&x_s[c * XROW + sb + 16];
        const ushort8 w3v = *(const ushort8*)&x_s[c * XROW + sb + 24];
        float xf[19];
        xf[0] = bf2f(w0v[7]);
        #pragma unroll
        for (int d = 0; d < 8; ++d) xf[1 + d] = bf2f(w1v[d]);
        #pragma unroll
        for (int d = 0; d < 8; ++d) xf[9 + d] = bf2f(w2v[d]);
        xf[17] = bf2f(w3v[0]);
        xf[18] = bf2f(w3v[1]);

        const float a0 = wa[cc * 3], a1 = wa[cc * 3 + 1], a2 = wa[cc * 3 + 2];
        const float b0 = wb[cc * 3], b1 = wb[cc * 3 + 1], b2 = wb[cc * 3 + 2];
        #pragma unroll
        for (int i = 0; i < 16; ++i) {
          const float xm = xf[i], x0 = xf[i + 1], xp = xf[i + 2];
          acc1[i] = fmaf(a0, xm, fmaf(a1, x0, fmaf(a2, xp, acc1[i])));
          acc3[i] = fmaf(b0, xm, fmaf(b1, x0, fmaf(b2, xp, acc3[i])));
        }
      }
    }

    ushort8 o1a, o1b, o3a, o3b;
    #pragma unroll
    for (int i = 0; i < 8; ++i) {
      float v1 = acc1[i];     v1 = v1 >= 0.f ? v1 : 0.01f * v1;
      float v3 = acc3[i];     v3 = v3 >= 0.f ? v3 : 0.01f * v3;
      o1a[i] = f2bf(v1); o3a[i] = f2bf(v3);
      float u1 = acc1[i + 8]; u1 = u1 >= 0.f ? u1 : 0.01f * u1;
      float u3 = acc3[i + 8]; u3 = u3 >= 0.f ? u3 : 0.01f * u3;
      o1b[i] = f2bf(u1); o3b[i] = f2bf(u3);
    }
    *(ushort8*)&h1_s[8 + h * HROW + sb]     = o1a;
    *(ushort8*)&h1_s[8 + h * HROW + sb + 8] = o1b;
    *(ushort8*)&h3_s[8 + h * HROW + sb]     = o3a;
    *(ushort8*)&h3_s[8 + h * HROW + sb + 8] = o3b;
  }
  __syncthreads();

  {
    const int lane = tid & 63;
    const int wid = __builtin_amdgcn_readfirstlane(tid >> 6);
    const int s = lane;
    const float* w1b_p = w1b + (size_t)p * (CH * HIDN);
    const float* w3b_p = w3b + (size_t)p * (CH * HIDN * 3);
    float* outp = out + (size_t)bid * CH;

    for (int q = 0; q < 16; ++q) {
      const int c0 = wid * 64 + q * 4;
      float l1[4] = {0.f, 0.f, 0.f, 0.f};
      float l3[4] = {0.f, 0.f, 0.f, 0.f};

      for (int h4 = 0; h4 < HIDN; h4 += 4) {
        float h1v[4], h3a[4], h3b[4], h3c[4];
        #pragma unroll
        for (int u = 0; u < 4; ++u) {
          const int hh = h4 + u;
          h1v[u] = bf2f(h1_s[8 + hh * HROW + s]);
          h3a[u] = bf2f(h3_s[7 + hh * HROW + s]);
          h3b[u] = bf2f(h3_s[8 + hh * HROW + s]);
          h3c[u] = bf2f(h3_s[9 + hh * HROW + s]);
        }
        #pragma unroll
        for (int j = 0; j < 4; ++j) {
          const int c = c0 + j;
          const float4 wv  = *(const float4*)&w1b_p[c * HIDN + h4];
          const float* w3  = &w3b_p[(size_t)(c * HIDN + h4) * 3];
          const float4 w30 = *(const float4*)w3;
          const float4 w31 = *(const float4*)(w3 + 4);
          const float4 w32 = *(const float4*)(w3 + 8);
          float ww[12];
          ww[0]=w30.x; ww[1]=w30.y; ww[2]=w30.z; ww[3]=w30.w;
          ww[4]=w31.x; ww[5]=w31.y; ww[6]=w31.z; ww[7]=w31.w;
          ww[8]=w32.x; ww[9]=w32.y; ww[10]=w32.z; ww[11]=w32.w;
          l1[j] = fmaf(wv.x, h1v[0], fmaf(wv.y, h1v[1],
                  fmaf(wv.z, h1v[2], fmaf(wv.w, h1v[3], l1[j]))));
          #pragma unroll
          for (int u = 0; u < 4; ++u) {
            l3[j] = fmaf(ww[u * 3], h3a[u],
                    fmaf(ww[u * 3 + 1], h3b[u],
                    fmaf(ww[u * 3 + 2], h3c[u], l3[j])));
          }
        }
      }

      #pragma unroll
      for (int j = 0; j < 4; ++j) {
        const int c = c0 + j;
        const u16* xr = &x_s[8 + c * XROW];
        const float xm2 = bf2f(xr[s - 2]);
        const float xm1 = bf2f(xr[s - 1]);
        const float x0  = bf2f(xr[s]);
        const float xp1 = bf2f(xr[s + 1]);
        const float xp2 = bf2f(xr[s + 2]);
        const float NI = -INFINITY;
        const float mx3 = fmaxf(x0, fmaxf(s >= 1 ? xm1 : NI, s <= 62 ? xp1 : NI));
        const float mx5 = fmaxf(mx3, fmaxf(s >= 2 ? xm2 : NI, s <= 61 ? xp2 : NI));
        const float av3 = (xm1 + x0 + xp1) * (1.f / 3.f);
        const float av5 = (xm2 + xm1 + x0 + xp1 + xp2) * 0.2f;
        const float sg1 = 1.f / (1.f + __expf(-l1[j]));
        const float sg3 = 1.f / (1.f + __expf(-l3[j]));
        float feat = (av3 + mx3) * sg1 + (av5 + mx5) * sg3;
        #pragma unroll
        for (int off = 32; off >= 1; off >>= 1)
          feat = fmaxf(feat, __shfl_xor(feat, off));
        if (lane == 0) outp[c] = feat;
      }
    }
  }
}

extern "C" void kernel_launch(void* const* d_in, const int* in_sizes, int n_in,
                              void* d_out, int out_size, void* d_ws, size_t ws_size,
                              hipStream_t stream) {
  (void)in_sizes; (void)n_in; (void)out_size;
  const float* x   = (const float*)d_in[0];
  const float* w1a = (const float*)d_in[1];
  const float* w1b = (const float*)d_in[2];
  const float* w3a = (const float*)d_in[3];
  const float* w3b = (const float*)d_in[4];
  float* out = (float*)d_out;

  const size_t WS_NEED = 2621440ull * 2ull;  // 5 MB of bf16 weights
  if (ws_size >= WS_NEED) {
    u16* wsb = (u16*)d_ws;
    cvt_tap<<<1024, 256, 0, stream>>>(w1a, wsb,           3);  // W1A [p][t][h][c]
    cvt_tap<<<1024, 256, 0, stream>>>(w3a, wsb + 786432,  3);  // W3A [p][t][h][c]
    cvt_tap<<<1024, 256, 0, stream>>>(w1b, wsb + 1572864, 1);  // W1B [p][c][h]
    cvt_tap<<<1024, 256, 0, stream>>>(w3b, wsb + 1835008, 3);  // W3B [p][t][c][h]
    tfa_mfma<<<PARTS * NB, 256, 0, stream>>>(x, wsb, out);
  } else {
    tfa_kernel<<<PARTS * NB, 256, 0, stream>>>(x, w1a, w1b, w3a, w3b, out);
  }
}

// Round 9
// 136.110 us; speedup vs baseline: 2.3188x; 1.0060x over previous
//
#include <hip/hip_runtime.h>
#include <hip/hip_bf16.h>

#define PARTS 16
#define NB 128
#define CH 256
#define SL 64
#define HIDN 64

typedef unsigned short u16;
typedef unsigned int u32;
typedef unsigned short ushort8 __attribute__((ext_vector_type(8)));
typedef unsigned short ushort4v __attribute__((ext_vector_type(4)));
typedef __attribute__((ext_vector_type(8))) short short8v;
typedef __attribute__((ext_vector_type(4))) float f32x4;

__device__ __forceinline__ float bf2f(u16 u) {
  union { unsigned u; float f; } t; t.u = ((unsigned)u) << 16; return t.f;
}
__device__ __forceinline__ u16 f2bf(float f) {
  union { float f; unsigned u; } t; t.f = f;
  unsigned u = t.u;
  u += 0x7FFFu + ((u >> 16) & 1u);
  return (u16)(u >> 16);
}
// packed pair convert: low16 = bf16(a), high16 = bf16(b) -> v_cvt_pk_bf16_f32
__device__ __forceinline__ unsigned pk2bf(float a, float b) {
  float2 f; f.x = a; f.y = b;
  union { __hip_bfloat162 h; unsigned u; } cv;
  cv.h = __float22bfloat162_rn(f);
  return cv.u;
}

// ===================== weight conversion prepass =====================
// out[p][t][x] = bf16(in[p][x][t]);  NX = 16384 fixed, NT = 3 or 1.
__global__ void cvt_tap(const float* __restrict__ in, u16* __restrict__ out, int NT) {
  const int i = blockIdx.x * 256 + threadIdx.x;   // p*16384 + x, exact grid
  const int p = i >> 14, xid = i & 16383;
  const float* src = in + (size_t)i * NT;
  for (int t = 0; t < NT; ++t)
    out[(size_t)(p * NT + t) * 16384 + xid] = f2bf(src[t]);
}

// ===================== MFMA main kernel =====================
// r3 wave split (A: waves split h; B: waves split c) — minimal per-wave VMEM.
// ADDITIVE padded-stride LDS layouts (r9): no XOR swizzle. Every LDS address
// is per-lane base + compile-time immediate; r8's 4.7M bank conflicts came
// from the XOR layout's 16-row column reads, the padded stride rotates rows
// across banks instead (132 dwords/row -> 4-bank shift -> b128 reads hit the
// 8-dword/bank minimum).
//  XT[r][264]: r = s+2, rows 0..67 (s=-2..65), pad rows 0,1,66,67 = 0.
//    stride 264 elem = 528 B (16B-aligned). No oob selects in phase A/pools.
//  ht1/ht3[s][72]: 64 rows, stride 144 B. B3 taps clamp+zero (2/12 combos).
// LDS = 35904 + 2*9216 = 54336 -> 3 blocks/CU (empirically the best point:
// r4-r8 proved extra occupancy buys nothing here).
#define XSTR 264
#define HSTR 72

// __launch_bounds__(256, 2): effective VGPR cap = 256/arg2 = 128 (calibrated
// r4-r8: (512,6)->40, (512,3)->80, (256,4)->64, (256,2)->128). No-spill
// falsifier: WRITE_SIZE ~2 MB.
__global__ __launch_bounds__(256, 2) void tfa_mfma(
    const float* __restrict__ x,
    const u16* __restrict__ wsb,
    float* __restrict__ out)
{
  const u16* W1A = wsb;                 // [p][t][h][c]  786432
  const u16* W3A = wsb + 786432;        // [p][t][h][c]  786432
  const u16* W1B = wsb + 1572864;       // [p][c][h]     262144
  const u16* W3B = wsb + 1835008;       // [p][t][c][h]  786432

  __shared__ __attribute__((aligned(16))) u16 xt[68 * XSTR];   // 35904 B
  __shared__ __attribute__((aligned(16))) u16 ht1[64 * HSTR];  //  9216 B
  __shared__ __attribute__((aligned(16))) u16 ht3[64 * HSTR];  //  9216 B

  const int tid = threadIdx.x;
  const int bid = blockIdx.x;          // p*NB + n
  const int p = bid >> 7;
  const int lane = tid & 63;
  const int w = tid >> 6;              // wave id 0..3

  // ---- zero XT pad rows (0,1,66,67): 4 rows x 33 ushort8 chunks ----
  if (tid < 132) {
    const int r4 = tid / 33;           // 0..3
    const int chunk = tid - r4 * 33;
    const int r = (r4 < 2) ? r4 : r4 + 64;   // 0,1,66,67
    *(ushort8*)&xt[r * XSTR + chunk * 8] = (ushort8)0;
  }

  // ---- stage x -> XT rows 2..65 (transposed, bf16); lane = s, wave: 64 c ----
  {
    const float* xb = x + (size_t)bid * (CH * SL);
    const int s = lane;
    #pragma unroll
    for (int j = 0; j < 8; ++j) {
      const int c0 = w * 64 + j * 8;
      union { ushort8 v; unsigned u[4]; } ov;
      #pragma unroll
      for (int k = 0; k < 4; ++k) {
        const float fa = xb[(c0 + 2 * k) * 64 + s];
        const float fb = xb[(c0 + 2 * k + 1) * 64 + s];
        ov.u[k] = pk2bf(fa, fb);
      }
      *(ushort8*)&xt[(s + 2) * XSTR + c0] = ov.v;
    }
  }
  __syncthreads();

  const int cm = lane & 15;            // m/n fragment index
  const int kg = lane >> 4;            // k-group

  // ---- phase A: conv1 both branches; wave owns h-tile [w*16, w*16+16) ----
  {
    const int h = w * 16 + cm;
    f32x4 acc1[4], acc3[4];
    #pragma unroll
    for (int nt = 0; nt < 4; ++nt) { acc1[nt] = (f32x4)0.f; acc3[nt] = (f32x4)0.f; }

    #pragma unroll 2
    for (int ks = 0; ks < 8; ++ks) {
      const int kc = ks * 32 + kg * 8;
      short8v a1[3], a3[3];
      #pragma unroll
      for (int t = 0; t < 3; ++t) {
        a1[t] = *(const short8v*)&W1A[(size_t)((p * 3 + t) * 64 + h) * 256 + kc];
        a3[t] = *(const short8v*)&W3A[(size_t)((p * 3 + t) * 64 + h) * 256 + kc];
      }
      #pragma unroll
      for (int nt = 0; nt < 4; ++nt) {
        const int s = nt * 16 + cm;    // B-frag n index
        #pragma unroll
        for (int t = 0; t < 3; ++t) {
          // tap s+(t-1) -> XT row s+t+1 in [1,66]; pad rows provide zeros
          const short8v b = *(const short8v*)&xt[(s + t + 1) * XSTR + kc];
          acc1[nt] = __builtin_amdgcn_mfma_f32_16x16x32_bf16(a1[t], b, acc1[nt], 0, 0, 0);
          acc3[nt] = __builtin_amdgcn_mfma_f32_16x16x32_bf16(a3[t], b, acc3[nt], 0, 0, 0);
        }
      }
    }

    // epilogue: LeakyReLU -> bf16 -> ht[s][h] (D: col=lane&15 -> s, row -> h)
    const int hc = w * 16 + kg * 4;
    #pragma unroll
    for (int nt = 0; nt < 4; ++nt) {
      const int s = nt * 16 + cm;
      float v1[4], v3[4];
      #pragma unroll
      for (int q = 0; q < 4; ++q) {
        const float a = acc1[nt][q]; v1[q] = a >= 0.f ? a : 0.01f * a;
        const float bq = acc3[nt][q]; v3[q] = bq >= 0.f ? bq : 0.01f * bq;
      }
      union { ushort4v v; u32 u[2]; } o1, o3;
      o1.u[0] = pk2bf(v1[0], v1[1]); o1.u[1] = pk2bf(v1[2], v1[3]);
      o3.u[0] = pk2bf(v3[0], v3[1]); o3.u[1] = pk2bf(v3[2], v3[3]);
      *(ushort4v*)&ht1[s * HSTR + hc] = o1.v;
      *(ushort4v*)&ht3[s * HSTR + hc] = o3.v;
    }
  }
  __syncthreads();

  // ---- phase B: conv2 both branches + gates + pools, in mt-halves ----
  #pragma unroll 1
  for (int half = 0; half < 2; ++half) {
    f32x4 acc[2][4];
    #pragma unroll
    for (int mt = 0; mt < 2; ++mt)
      #pragma unroll
      for (int nt = 0; nt < 4; ++nt) acc[mt][nt] = (f32x4)0.f;

    // branch 1: K=64h, k1 conv (no shift, no OOB)
    #pragma unroll
    for (int ks = 0; ks < 2; ++ks) {
      const int kh = ks * 32 + kg * 8;
      short8v a[2];
      #pragma unroll
      for (int mt = 0; mt < 2; ++mt) {
        const int c = w * 64 + (half * 2 + mt) * 16 + cm;
        a[mt] = *(const short8v*)&W1B[((size_t)p * 256 + c) * 64 + kh];
      }
      #pragma unroll
      for (int nt = 0; nt < 4; ++nt) {
        const int s = nt * 16 + cm;
        const short8v b = *(const short8v*)&ht1[s * HSTR + kh];
        #pragma unroll
        for (int mt = 0; mt < 2; ++mt)
          acc[mt][nt] = __builtin_amdgcn_mfma_f32_16x16x32_bf16(a[mt], b, acc[mt][nt], 0, 0, 0);
      }
    }

    // gates g1 = sigmoid(L1), packed bf16 pairs
    u32 g1p[2][4][2];
    #pragma unroll
    for (int mt = 0; mt < 2; ++mt)
      #pragma unroll
      for (int nt = 0; nt < 4; ++nt) {
        #pragma unroll
        for (int j = 0; j < 2; ++j) {
          const float ga = 1.f / (1.f + __expf(-acc[mt][nt][2 * j]));
          const float gb = 1.f / (1.f + __expf(-acc[mt][nt][2 * j + 1]));
          g1p[mt][nt][j] = pk2bf(ga, gb);
        }
        acc[mt][nt] = (f32x4)0.f;      // reuse for branch 3
      }

    // branch 3: 3 tap-GEMMs; taps clamp+zero only at nt=0/t=0 and nt=3/t=2
    #pragma unroll
    for (int ks = 0; ks < 2; ++ks) {
      const int kh = ks * 32 + kg * 8;
      #pragma unroll
      for (int t = 0; t < 3; ++t) {
        short8v a[2];
        #pragma unroll
        for (int mt = 0; mt < 2; ++mt) {
          const int c = w * 64 + (half * 2 + mt) * 16 + cm;
          a[mt] = *(const short8v*)&W3B[(size_t)((p * 3 + t) * 256 + c) * 64 + kh];
        }
        #pragma unroll
        for (int nt = 0; nt < 4; ++nt) {
          const int s = nt * 16 + cm;
          const int r = s + t - 1;                   // may be -1 or 64
          const bool oob = (unsigned)r > 63u;        // compile-time false for inner nt/t
          const short8v bb = *(const short8v*)&ht3[(oob ? s : r) * HSTR + kh];
          const short8v b = oob ? (short8v)(short)0 : bb;   // H3 pad = 0
          #pragma unroll
          for (int mt = 0; mt < 2; ++mt)
            acc[mt][nt] = __builtin_amdgcn_mfma_f32_16x16x32_bf16(a[mt], b, acc[mt][nt], 0, 0, 0);
        }
      }
    }

    // epilogue: pools from XT (pad rows = zeros), gates, fused max over s
    #pragma unroll
    for (int mt = 0; mt < 2; ++mt) {
      const int c4 = w * 64 + (half * 2 + mt) * 16 + kg * 4;  // 4 consecutive c
      float fmx0 = -INFINITY, fmx1 = -INFINITY, fmx2 = -INFINITY, fmx3 = -INFINITY;
      #pragma unroll
      for (int nt = 0; nt < 4; ++nt) {
        const int sg = nt * 16 + cm;               // D col: global s
        // XT rows sg..sg+4 = (sg-2..sg+2)+2, all in [0,67]; pads are zero
        const ushort4v vm2 = *(const ushort4v*)&xt[(sg)     * XSTR + c4];
        const ushort4v vm1 = *(const ushort4v*)&xt[(sg + 1) * XSTR + c4];
        const ushort4v v0  = *(const ushort4v*)&xt[(sg + 2) * XSTR + c4];
        const ushort4v vp1 = *(const ushort4v*)&xt[(sg + 3) * XSTR + c4];
        const ushort4v vp2 = *(const ushort4v*)&xt[(sg + 4) * XSTR + c4];
        const float NI = -INFINITY;
        float ft[4];
        #pragma unroll
        for (int q = 0; q < 4; ++q) {
          const float xm2 = bf2f(vm2[q]), xm1 = bf2f(vm1[q]), x0 = bf2f(v0[q]);
          const float xp1 = bf2f(vp1[q]), xp2 = bf2f(vp2[q]);
          // avg: pad zeros already in XT (count_include_pad); max: exclude pads
          const float mx3 = fmaxf(x0, fmaxf(sg >= 1 ? xm1 : NI, sg <= 62 ? xp1 : NI));
          const float mx5 = fmaxf(mx3, fmaxf(sg >= 2 ? xm2 : NI, sg <= 61 ? xp2 : NI));
          const float av3 = (xm1 + x0 + xp1) * (1.f / 3.f);
          const float av5 = (xm2 + xm1 + x0 + xp1 + xp2) * 0.2f;
          const float g1 = bf2f((u16)(g1p[mt][nt][q >> 1] >> ((q & 1) * 16)));
          const float g3 = 1.f / (1.f + __expf(-acc[mt][nt][q]));
          ft[q] = (av3 + mx3) * g1 + (av5 + mx5) * g3;
        }
        fmx0 = fmaxf(fmx0, ft[0]); fmx1 = fmaxf(fmx1, ft[1]);
        fmx2 = fmaxf(fmx2, ft[2]); fmx3 = fmaxf(fmx3, ft[3]);
      }
      // reduce max across the 16 lanes of each row-group (xor bits 0..3)
      #pragma unroll
      for (int off = 1; off < 16; off <<= 1) {
        fmx0 = fmaxf(fmx0, __shfl_xor(fmx0, off));
        fmx1 = fmaxf(fmx1, __shfl_xor(fmx1, off));
        fmx2 = fmaxf(fmx2, __shfl_xor(fmx2, off));
        fmx3 = fmaxf(fmx3, __shfl_xor(fmx3, off));
      }
      if (cm == 0) {
        float4 o; o.x = fmx0; o.y = fmx1; o.z = fmx2; o.w = fmx3;
        *(float4*)&out[(size_t)bid * 256 + c4] = o;
      }
    }
  }
}

// ===================== fallback vector kernel (round-1, correct) =====================
#define XROW 72
#define HROW 72

__global__ __launch_bounds__(256, 2) void tfa_kernel(
    const float* __restrict__ x,
    const float* __restrict__ w1a,
    const float* __restrict__ w1b,
    const float* __restrict__ w3a,
    const float* __restrict__ w3b,
    float* __restrict__ out)
{
  __shared__ __attribute__((aligned(16))) u16 x_s[8 + CH * XROW];
  __shared__ __attribute__((aligned(16))) u16 h1_s[8 + HIDN * HROW];
  __shared__ __attribute__((aligned(16))) u16 h3_s[8 + HIDN * HROW];

  const int tid = threadIdx.x;
  const int bid = blockIdx.x;
  const int p = bid >> 7;

  {
    const ushort8 z = {0, 0, 0, 0, 0, 0, 0, 0};
    for (int i = tid; i < 257; i += 256) {
      u16* dst = (i == 0) ? &x_s[0] : &x_s[8 + (i - 1) * XROW + 64];
      *(ushort8*)dst = z;
    }
    if (tid < 65) {
      u16* d1 = (tid == 0) ? &h1_s[0] : &h1_s[8 + (tid - 1) * HROW + 64];
      *(ushort8*)d1 = z;
      u16* d3 = (tid == 0) ? &h3_s[0] : &h3_s[8 + (tid - 1) * HROW + 64];
      *(ushort8*)d3 = z;
    }
  }

  const float* xblk = x + (size_t)bid * (CH * SL);
  #pragma unroll
  for (int j = 0; j < 16; ++j) {
    const int g = tid + 256 * j;
    const float4 v = ((const float4*)xblk)[g];
    const int c = g >> 4, s4 = g & 15;
    ushort4v o;
    o[0] = f2bf(v.x); o[1] = f2bf(v.y); o[2] = f2bf(v.z); o[3] = f2bf(v.w);
    *(ushort4v*)&x_s[8 + c * XROW + s4 * 4] = o;
  }
  __syncthreads();

  {
    const int h = tid >> 2;
    const int sg = tid & 3;
    const int sb = sg << 4;
    float acc1[16], acc3[16];
    #pragma unroll
    for (int i = 0; i < 16; ++i) { acc1[i] = 0.f; acc3[i] = 0.f; }

    const float* w1a_p = w1a + ((size_t)p * HIDN + h) * (CH * 3);
    const float* w3a_p = w3a + ((size_t)p * HIDN + h) * (CH * 3);

    for (int c4 = 0; c4 < CH; c4 += 4) {
      const float4 a0v = *(const float4*)&w1a_p[c4 * 3];
      const float4 a1v = *(const float4*)&w1a_p[c4 * 3 + 4];
      const float4 a2v = *(const float4*)&w1a_p[c4 * 3 + 8];
      const float4 b0v = *(const float4*)&w3a_p[c4 * 3];
      const float4 b1v = *(const float4*)&w3a_p[c4 * 3 + 4];
      const float4 b2v = *(const float4*)&w3a_p[c4 * 3 + 8];
      float wa[12], wb[12];
      wa[0]=a0v.x; wa[1]=a0v.y; wa[2]=a0v.z; wa[3]=a0v.w;
      wa[4]=a1v.x; wa[5]=a1v.y; wa[6]=a1v.z; wa[7]=a1v.w;
      wa[8]=a2v.x; wa[9]=a2v.y; wa[10]=a2v.z; wa[11]=a2v.w;
      wb[0]=b0v.x; wb[1]=b0v.y; wb[2]=b0v.z; wb[3]=b0v.w;
      wb[4]=b1v.x; wb[5]=b1v.y; wb[6]=b1v.z; wb[7]=b1v.w;
      wb[8]=b2v.x; wb[9]=b2v.y; wb[10]=b2v.z; wb[11]=b2v.w;

      #pragma unroll
      for (int cc = 0; cc < 4; ++cc) {
        const int c = c4 + cc;
        const ushort8 w0v = *(const ushort8*)&x_s[c * XROW + sb];
        const ushort8 w1v = *(const ushort8*)&x_s[c * XROW + sb + 8];
        const ushort8 w2v = *(const ushort8*)&x_s[c * XROW + sb + 16];
        const ushort8 w3v = *(const ushort8*)&x_s[c * XROW + sb + 24];
        float xf[19];
        xf[0] = bf2f(w0v[7]);
        #pragma unroll
        for (int d = 0; d < 8; ++d) xf[1 + d] = bf2f(w1v[d]);
        #pragma unroll
        for (int d = 0; d < 8; ++d) xf[9 + d] = bf2f(w2v[d]);
        xf[17] = bf2f(w3v[0]);
        xf[18] = bf2f(w3v[1]);

        const float a0 = wa[cc * 3], a1 = wa[cc * 3 + 1], a2 = wa[cc * 3 + 2];
        const float b0 = wb[cc * 3], b1 = wb[cc * 3 + 1], b2 = wb[cc * 3 + 2];
        #pragma unroll
        for (int i = 0; i < 16; ++i) {
          const float xm = xf[i], x0 = xf[i + 1], xp = xf[i + 2];
          acc1[i] = fmaf(a0, xm, fmaf(a1, x0, fmaf(a2, xp, acc1[i])));
          acc3[i] = fmaf(b0, xm, fmaf(b1, x0, fmaf(b2, xp, acc3[i])));
        }
      }
    }

    ushort8 o1a, o1b, o3a, o3b;
    #pragma unroll
    for (int i = 0; i < 8; ++i) {
      float v1 = acc1[i];     v1 = v1 >= 0.f ? v1 : 0.01f * v1;
      float v3 = acc3[i];     v3 = v3 >= 0.f ? v3 : 0.01f * v3;
      o1a[i] = f2bf(v1); o3a[i] = f2bf(v3);
      float u1 = acc1[i + 8]; u1 = u1 >= 0.f ? u1 : 0.01f * u1;
      float u3 = acc3[i + 8]; u3 = u3 >= 0.f ? u3 : 0.01f * u3;
      o1b[i] = f2bf(u1); o3b[i] = f2bf(u3);
    }
    *(ushort8*)&h1_s[8 + h * HROW + sb]     = o1a;
    *(ushort8*)&h1_s[8 + h * HROW + sb + 8] = o1b;
    *(ushort8*)&h3_s[8 + h * HROW + sb]     = o3a;
    *(ushort8*)&h3_s[8 + h * HROW + sb + 8] = o3b;
  }
  __syncthreads();

  {
    const int lane = tid & 63;
    const int wid = __builtin_amdgcn_readfirstlane(tid >> 6);
    const int s = lane;
    const float* w1b_p = w1b + (size_t)p * (CH * HIDN);
    const float* w3b_p = w3b + (size_t)p * (CH * HIDN * 3);
    float* outp = out + (size_t)bid * CH;

    for (int q = 0; q < 16; ++q) {
      const int c0 = wid * 64 + q * 4;
      float l1[4] = {0.f, 0.f, 0.f, 0.f};
      float l3[4] = {0.f, 0.f, 0.f, 0.f};

      for (int h4 = 0; h4 < HIDN; h4 += 4) {
        float h1v[4], h3a[4], h3b[4], h3c[4];
        #pragma unroll
        for (int u = 0; u < 4; ++u) {
          const int hh = h4 + u;
          h1v[u] = bf2f(h1_s[8 + hh * HROW + s]);
          h3a[u] = bf2f(h3_s[7 + hh * HROW + s]);
          h3b[u] = bf2f(h3_s[8 + hh * HROW + s]);
          h3c[u] = bf2f(h3_s[9 + hh * HROW + s]);
        }
        #pragma unroll
        for (int j = 0; j < 4; ++j) {
          const int c = c0 + j;
          const float4 wv  = *(const float4*)&w1b_p[c * HIDN + h4];
          const float* w3  = &w3b_p[(size_t)(c * HIDN + h4) * 3];
          const float4 w30 = *(const float4*)w3;
          const float4 w31 = *(const float4*)(w3 + 4);
          const float4 w32 = *(const float4*)(w3 + 8);
          float ww[12];
          ww[0]=w30.x; ww[1]=w30.y; ww[2]=w30.z; ww[3]=w30.w;
          ww[4]=w31.x; ww[5]=w31.y; ww[6]=w31.z; ww[7]=w31.w;
          ww[8]=w32.x; ww[9]=w32.y; ww[10]=w32.z; ww[11]=w32.w;
          l1[j] = fmaf(wv.x, h1v[0], fmaf(wv.y, h1v[1],
                  fmaf(wv.z, h1v[2], fmaf(wv.w, h1v[3], l1[j]))));
          #pragma unroll
          for (int u = 0; u < 4; ++u) {
            l3[j] = fmaf(ww[u * 3], h3a[u],
                    fmaf(ww[u * 3 + 1], h3b[u],
                    fmaf(ww[u * 3 + 2], h3c[u], l3[j])));
          }
        }
      }

      #pragma unroll
      for (int j = 0; j < 4; ++j) {
        const int c = c0 + j;
        const u16* xr = &x_s[8 + c * XROW];
        const float xm2 = bf2f(xr[s - 2]);
        const float xm1 = bf2f(xr[s - 1]);
        const float x0  = bf2f(xr[s]);
        const float xp1 = bf2f(xr[s + 1]);
        const float xp2 = bf2f(xr[s + 2]);
        const float NI = -INFINITY;
        const float mx3 = fmaxf(x0, fmaxf(s >= 1 ? xm1 : NI, s <= 62 ? xp1 : NI));
        const float mx5 = fmaxf(mx3, fmaxf(s >= 2 ? xm2 : NI, s <= 61 ? xp2 : NI));
        const float av3 = (xm1 + x0 + xp1) * (1.f / 3.f);
        const float av5 = (xm2 + xm1 + x0 + xp1 + xp2) * 0.2f;
        const float sg1 = 1.f / (1.f + __expf(-l1[j]));
        const float sg3 = 1.f / (1.f + __expf(-l3[j]));
        float feat = (av3 + mx3) * sg1 + (av5 + mx5) * sg3;
        #pragma unroll
        for (int off = 32; off >= 1; off >>= 1)
          feat = fmaxf(feat, __shfl_xor(feat, off));
        if (lane == 0) outp[c] = feat;
      }
    }
  }
}

extern "C" void kernel_launch(void* const* d_in, const int* in_sizes, int n_in,
                              void* d_out, int out_size, void* d_ws, size_t ws_size,
                              hipStream_t stream) {
  (void)in_sizes; (void)n_in; (void)out_size;
  const float* x   = (const float*)d_in[0];
  const float* w1a = (const float*)d_in[1];
  const float* w1b = (const float*)d_in[2];
  const float* w3a = (const float*)d_in[3];
  const float* w3b = (const float*)d_in[4];
  float* out = (float*)d_out;

  const size_t WS_NEED = 2621440ull * 2ull;  // 5 MB of bf16 weights
  if (ws_size >= WS_NEED) {
    u16* wsb = (u16*)d_ws;
    cvt_tap<<<1024, 256, 0, stream>>>(w1a, wsb,           3);  // W1A [p][t][h][c]
    cvt_tap<<<1024, 256, 0, stream>>>(w3a, wsb + 786432,  3);  // W3A [p][t][h][c]
    cvt_tap<<<1024, 256, 0, stream>>>(w1b, wsb + 1572864, 1);  // W1B [p][c][h]
    cvt_tap<<<1024, 256, 0, stream>>>(w3b, wsb + 1835008, 3);  // W3B [p][t][c][h]
    tfa_mfma<<<PARTS * NB, 256, 0, stream>>>(x, wsb, out);
  } else {
    tfa_kernel<<<PARTS * NB, 256, 0, stream>>>(x, w1a, w1b, w3a, w3b, out);
  }
}